// Round 2
// baseline (4233.524 us; speedup 1.0000x reference)
//
#include <hip/hip_runtime.h>

// ---------------------------------------------------------------------------
// GCN: 3x (GCNConv -> BatchNorm -> ReLU) -> global_add_pool -> MLP
// Adaptive workspace: fp32 path (~310MB) or compact bf16-storage path (~207MB).
//
// Math (equal to reference up to reordering):
//   xs   = (h @ W) * dinv[row]                       (GEMM epilogue scale)
//   agg  = scatter_add(xs[src] -> dst)               (plain sums, no coeffs)
//   t    = dinv[row] * (agg + xs) + b                (pre-BN activation)
//   h'   = relu(t * g*rsqrt(var+eps) + (be - mean*...))
// ---------------------------------------------------------------------------

__device__ inline float bf2f(unsigned short u) {
    union { unsigned int i; float f; } v; v.i = ((unsigned int)u) << 16; return v.f;
}
__device__ inline unsigned short f2bf(float f) {
    unsigned int x = __float_as_uint(f);
    unsigned int r = (x + 0x7FFFu + ((x >> 16) & 1u)) >> 16;
    return (unsigned short)r;
}

template<typename T> __device__ inline float ld1(const T* p);
template<> __device__ inline float ld1<float>(const float* p) { return *p; }
template<> __device__ inline float ld1<unsigned short>(const unsigned short* p) { return bf2f(*p); }

template<typename T> __device__ inline float4 ld4(const T* p);
template<> __device__ inline float4 ld4<float>(const float* p) { return *(const float4*)p; }
template<> __device__ inline float4 ld4<unsigned short>(const unsigned short* p) {
    ushort4 u = *(const ushort4*)p;
    return make_float4(bf2f(u.x), bf2f(u.y), bf2f(u.z), bf2f(u.w));
}

template<typename T> __device__ inline void st4(T* p, float4 v);
template<> __device__ inline void st4<float>(float* p, float4 v) { *(float4*)p = v; }
template<> __device__ inline void st4<unsigned short>(unsigned short* p, float4 v) {
    ushort4 u; u.x = f2bf(v.x); u.y = f2bf(v.y); u.z = f2bf(v.z); u.w = f2bf(v.w);
    *(ushort4*)p = u;
}

// ---- degree ----------------------------------------------------------------
__global__ void count_deg(const int* __restrict__ dst, float* __restrict__ deg, int E) {
    int i = blockIdx.x * blockDim.x + threadIdx.x;
    int stride = gridDim.x * blockDim.x;
    for (; i < E; i += stride) atomicAdd(&deg[dst[i]], 1.0f);
}

__global__ void finish_dinv(float* __restrict__ deg, int N) {
    int i = blockIdx.x * blockDim.x + threadIdx.x;
    if (i < N) deg[i] = rsqrtf(deg[i] + 1.0f);
}

// ---- SGEMM: C[M,256] = (A[M,K] @ W[K,256]) * dinv[row], 128x128 tile -------
template<typename TA, typename TC>
__global__ __launch_bounds__(256) void gemm_xs(
    const TA* __restrict__ A, const float* __restrict__ W,
    const float* __restrict__ dinv, TC* __restrict__ C, int M, int K)
{
    const int Nd = 256;
    __shared__ float As[16][132];   // As[k][m]
    __shared__ float Bs[16][128];

    const int tid = threadIdx.x;
    const int bm = blockIdx.x * 128;
    const int bn = blockIdx.y * 128;
    const int tr = (tid >> 4) << 3;
    const int tc = (tid & 15) << 3;
    const int arow = tid >> 2;
    const int acol = (tid & 3) << 2;
    const int wrow = tid >> 4;
    const int wcol = (tid & 15) << 2;

    float acc[8][8];
    #pragma unroll
    for (int i = 0; i < 8; ++i)
        #pragma unroll
        for (int j = 0; j < 8; ++j) acc[i][j] = 0.f;

    for (int k0 = 0; k0 < K; k0 += 16) {
        #pragma unroll
        for (int h = 0; h < 2; ++h) {
            int r = bm + arow + h * 64;
            float4 av = make_float4(0.f, 0.f, 0.f, 0.f);
            if (r < M) av = ld4(A + (size_t)r * K + k0 + acol);
            As[acol + 0][arow + h * 64] = av.x;
            As[acol + 1][arow + h * 64] = av.y;
            As[acol + 2][arow + h * 64] = av.z;
            As[acol + 3][arow + h * 64] = av.w;
        }
        #pragma unroll
        for (int h = 0; h < 2; ++h) {
            float4 wv = *(const float4*)(W + (size_t)(k0 + wrow) * Nd + bn + wcol + h * 64);
            *(float4*)&Bs[wrow][wcol + h * 64] = wv;
        }
        __syncthreads();
        #pragma unroll
        for (int k = 0; k < 16; ++k) {
            float4 a0 = *(const float4*)&As[k][tr];
            float4 a1 = *(const float4*)&As[k][tr + 4];
            float4 b0 = *(const float4*)&Bs[k][tc];
            float4 b1 = *(const float4*)&Bs[k][tc + 4];
            float a[8] = {a0.x, a0.y, a0.z, a0.w, a1.x, a1.y, a1.z, a1.w};
            float b[8] = {b0.x, b0.y, b0.z, b0.w, b1.x, b1.y, b1.z, b1.w};
            #pragma unroll
            for (int i = 0; i < 8; ++i)
                #pragma unroll
                for (int j = 0; j < 8; ++j)
                    acc[i][j] = fmaf(a[i], b[j], acc[i][j]);
        }
        __syncthreads();
    }
    #pragma unroll
    for (int i = 0; i < 8; ++i) {
        int r = bm + tr + i;
        if (r < M) {
            float sc = dinv[r];
            TC* cp = C + (size_t)r * Nd + bn + tc;
            st4(cp + 0, make_float4(acc[i][0] * sc, acc[i][1] * sc, acc[i][2] * sc, acc[i][3] * sc));
            st4(cp + 4, make_float4(acc[i][4] * sc, acc[i][5] * sc, acc[i][6] * sc, acc[i][7] * sc));
        }
    }
}

// ---- edge scatter: agg[dst] += xs[src]  (plain sums, H=256) ----------------
template<typename TS>
__global__ __launch_bounds__(256) void scatter_edges(
    const TS* __restrict__ xs, const int* __restrict__ src,
    const int* __restrict__ dst, float* __restrict__ agg, int E)
{
    const int lane = threadIdx.x & 63;
    int wid = (blockIdx.x * blockDim.x + threadIdx.x) >> 6;
    const int nw = (gridDim.x * blockDim.x) >> 6;
    for (int e = wid; e < E; e += nw) {
        int s = src[e], d = dst[e];
        float4 v = ld4(xs + (size_t)s * 256 + lane * 4);
        float* ap = agg + (size_t)d * 256 + lane * 4;
        atomicAdd(ap + 0, v.x);
        atomicAdd(ap + 1, v.y);
        atomicAdd(ap + 2, v.z);
        atomicAdd(ap + 3, v.w);
    }
}

// ---- t = dinv*(agg + xs) + b (in place on agg) + column stats --------------
template<typename TS>
__global__ __launch_bounds__(256) void bn_stats(
    float* __restrict__ agg, const TS* __restrict__ xs,
    const float* __restrict__ dinv, const float* __restrict__ b,
    float* __restrict__ stats, int N)
{
    const int f = threadIdx.x;
    const float bf = b[f];
    float sum = 0.f, sq = 0.f;
    for (int r = blockIdx.x; r < N; r += gridDim.x) {
        float di = dinv[r];
        size_t o = (size_t)r * 256 + f;
        float t = di * (agg[o] + ld1(xs + o)) + bf;
        agg[o] = t;
        sum += t;
        sq += t * t;
    }
    atomicAdd(&stats[f], sum);
    atomicAdd(&stats[256 + f], sq);
}

__global__ void bn_finalize(const float* __restrict__ stats,
                            const float* __restrict__ g, const float* __restrict__ be,
                            float* __restrict__ ss, int N)
{
    int f = threadIdx.x;
    float m = stats[f] / (float)N;
    float v = stats[256 + f] / (float)N - m * m;
    float sc = g[f] * rsqrtf(v + 1e-5f);
    ss[f] = sc;
    ss[256 + f] = be[f] - m * sc;
}

// ---- h = relu(t*scale + shift) ---------------------------------------------
template<typename TH>
__global__ __launch_bounds__(256) void bn_apply(
    const float* __restrict__ agg, const float* __restrict__ ss,
    TH* __restrict__ out, int N)
{
    const float4* a4 = (const float4*)agg;
    const float4* sc4 = (const float4*)ss;
    const float4* sh4 = (const float4*)(ss + 256);
    size_t total = (size_t)N * 64;
    size_t stride = (size_t)gridDim.x * blockDim.x;
    for (size_t i = blockIdx.x * (size_t)blockDim.x + threadIdx.x; i < total; i += stride) {
        int c = (int)(i & 63);
        float4 a = a4[i], s = sc4[c], h = sh4[c];
        float4 r;
        r.x = fmaxf(fmaf(a.x, s.x, h.x), 0.f);
        r.y = fmaxf(fmaf(a.y, s.y, h.y), 0.f);
        r.z = fmaxf(fmaf(a.z, s.z, h.z), 0.f);
        r.w = fmaxf(fmaf(a.w, s.w, h.w), 0.f);
        st4(out + i * 4, r);
    }
}

// ---- global add pool (H=256) -----------------------------------------------
template<typename TH>
__global__ __launch_bounds__(256) void pool_add(
    const TH* __restrict__ h, const int* __restrict__ batch,
    float* __restrict__ pooled, int N)
{
    size_t total = (size_t)N * 64;
    size_t stride = (size_t)gridDim.x * blockDim.x;
    for (size_t i = blockIdx.x * (size_t)blockDim.x + threadIdx.x; i < total; i += stride) {
        int r = (int)(i >> 6), c4 = (int)(i & 63) * 4;
        float4 v = ld4(h + (size_t)r * 256 + c4);
        int g = batch[r];
        float* p = pooled + (size_t)g * 256 + c4;
        atomicAdd(p + 0, v.x);
        atomicAdd(p + 1, v.y);
        atomicAdd(p + 2, v.z);
        atomicAdd(p + 3, v.w);
    }
}

// ---- fused MLP --------------------------------------------------------------
__global__ __launch_bounds__(256) void mlp_fused(
    const float* __restrict__ pooled,
    const float* __restrict__ LW1, const float* __restrict__ Lb1,
    const float* __restrict__ LW2, const float* __restrict__ Lb2,
    float* __restrict__ out)
{
    __shared__ float sp[256];
    __shared__ float red[256];
    const int g = blockIdx.x;
    const int t = threadIdx.x;
    sp[t] = pooled[(size_t)g * 256 + t];
    __syncthreads();
    float acc = Lb1[t];
    #pragma unroll 8
    for (int k = 0; k < 256; ++k) acc = fmaf(sp[k], LW1[k * 256 + t], acc);
    acc = fmaxf(acc, 0.f);
    red[t] = acc * LW2[t];
    __syncthreads();
    for (int s = 128; s > 0; s >>= 1) {
        if (t < s) red[t] += red[t + s];
        __syncthreads();
    }
    if (t == 0) out[g] = red[0] + Lb2[0];
}

// ---------------------------------------------------------------------------
extern "C" void kernel_launch(void* const* d_in, const int* in_sizes, int n_in,
                              void* d_out, int out_size, void* d_ws, size_t ws_size,
                              hipStream_t stream)
{
    const float* x    = (const float*)d_in[0];
    const int*   ei   = (const int*)d_in[1];
    const int*   batch= (const int*)d_in[2];
    const float* W1 = (const float*)d_in[3];  const float* b1 = (const float*)d_in[4];
    const float* W2 = (const float*)d_in[5];  const float* b2 = (const float*)d_in[6];
    const float* W3 = (const float*)d_in[7];  const float* b3 = (const float*)d_in[8];
    const float* g1 = (const float*)d_in[9];  const float* be1= (const float*)d_in[10];
    const float* g2 = (const float*)d_in[11]; const float* be2= (const float*)d_in[12];
    const float* g3 = (const float*)d_in[13]; const float* be3= (const float*)d_in[14];
    const float* LW1= (const float*)d_in[15]; const float* Lb1= (const float*)d_in[16];
    const float* LW2= (const float*)d_in[17]; const float* Lb2= (const float*)d_in[18];

    const int N = in_sizes[2];            // 100000
    const int E = in_sizes[1] / 2;        // 300000
    const int F = in_sizes[0] / N;        // 128
    const int H = in_sizes[4];            // 256
    const int G = out_size;               // 2048
    const int* src = ei;
    const int* dst = ei + E;
    const size_t NH = (size_t)N * H;

    const size_t aux_bytes = ((size_t)N * 4 + 255 & ~(size_t)255) + 2048 + 2048
                           + (size_t)G * H * 4 + 4096;
    const size_t need_fp32 = 3 * NH * 4 + aux_bytes;

    const float* Wl[3] = {W1, W2, W3};
    const float* bl[3] = {b1, b2, b3};
    const float* gl[3] = {g1, g2, g3};
    const float* bel[3]= {be1, be2, be3};

    char* p = (char*)d_ws;
    float* AGG = (float*)p;  p += NH * 4;

    if (ws_size >= need_fp32) {
        // -------- fp32 path --------
        float* XS = (float*)p;  p += NH * 4;
        float* HB = (float*)p;  p += NH * 4;
        float* dinv = (float*)p; p += ((size_t)N * 4 + 255) & ~(size_t)255;
        float* stats = (float*)p; p += 2048;
        float* ss = (float*)p;    p += 2048;
        float* pooled = (float*)p;

        hipMemsetAsync(dinv, 0, (size_t)N * sizeof(float), stream);
        count_deg<<<1024, 256, 0, stream>>>(dst, dinv, E);
        finish_dinv<<<(N + 255) / 256, 256, 0, stream>>>(dinv, N);

        for (int L = 0; L < 3; ++L) {
            dim3 grid((N + 127) / 128, H / 128);
            if (L == 0)
                gemm_xs<float, float><<<grid, 256, 0, stream>>>(x, Wl[L], dinv, XS, N, F);
            else
                gemm_xs<float, float><<<grid, 256, 0, stream>>>(HB, Wl[L], dinv, XS, N, H);
            hipMemsetAsync(AGG, 0, NH * sizeof(float), stream);
            scatter_edges<float><<<4096, 256, 0, stream>>>(XS, src, dst, AGG, E);
            hipMemsetAsync(stats, 0, 512 * sizeof(float), stream);
            bn_stats<float><<<1024, 256, 0, stream>>>(AGG, XS, dinv, bl[L], stats, N);
            bn_finalize<<<1, 256, 0, stream>>>(stats, gl[L], bel[L], ss, N);
            bn_apply<float><<<2048, 256, 0, stream>>>(AGG, ss, HB, N);
        }
        hipMemsetAsync(pooled, 0, (size_t)G * H * sizeof(float), stream);
        pool_add<float><<<2048, 256, 0, stream>>>(HB, batch, pooled, N);
        mlp_fused<<<G, 256, 0, stream>>>(pooled, LW1, Lb1, LW2, Lb2, (float*)d_out);
    } else {
        // -------- compact path: xs/h stored bf16, agg fp32 --------
        unsigned short* XS = (unsigned short*)p;  p += NH * 2;
        unsigned short* HB = (unsigned short*)p;  p += NH * 2;
        float* dinv = (float*)p; p += ((size_t)N * 4 + 255) & ~(size_t)255;
        float* stats = (float*)p; p += 2048;
        float* ss = (float*)p;    p += 2048;
        float* pooled = (float*)p;

        hipMemsetAsync(dinv, 0, (size_t)N * sizeof(float), stream);
        count_deg<<<1024, 256, 0, stream>>>(dst, dinv, E);
        finish_dinv<<<(N + 255) / 256, 256, 0, stream>>>(dinv, N);

        for (int L = 0; L < 3; ++L) {
            dim3 grid((N + 127) / 128, H / 128);
            if (L == 0)
                gemm_xs<float, unsigned short><<<grid, 256, 0, stream>>>(x, Wl[L], dinv, XS, N, F);
            else
                gemm_xs<unsigned short, unsigned short><<<grid, 256, 0, stream>>>(HB, Wl[L], dinv, XS, N, H);
            hipMemsetAsync(AGG, 0, NH * sizeof(float), stream);
            scatter_edges<unsigned short><<<4096, 256, 0, stream>>>(XS, src, dst, AGG, E);
            hipMemsetAsync(stats, 0, 512 * sizeof(float), stream);
            bn_stats<unsigned short><<<1024, 256, 0, stream>>>(AGG, XS, dinv, bl[L], stats, N);
            bn_finalize<<<1, 256, 0, stream>>>(stats, gl[L], bel[L], ss, N);
            bn_apply<unsigned short><<<2048, 256, 0, stream>>>(AGG, ss, HB, N);
        }
        hipMemsetAsync(pooled, 0, (size_t)G * H * sizeof(float), stream);
        pool_add<unsigned short><<<2048, 256, 0, stream>>>(HB, batch, pooled, N);
        mlp_fused<<<G, 256, 0, stream>>>(pooled, LW1, Lb1, LW2, Lb2, (float*)d_out);
    }
}

// Round 3
// 1075.278 us; speedup vs baseline: 3.9371x; 3.9371x over previous
//
#include <hip/hip_runtime.h>

// ---------------------------------------------------------------------------
// GCN: 3x (GCNConv -> BatchNorm -> ReLU) -> global_add_pool -> MLP
// Compact path: xs/h stored bf16, agg/t fp32. CSR-gather aggregation
// (no feature atomics). Fallback to atomic scatter if ws too small.
//
// Math (equal to reference up to reordering):
//   xs   = (h @ W) * dinv[row]
//   t    = dinv[n] * (xs[n] + sum_{e: dst=n} xs[src_e]) + b
//   h'   = relu(t * g*rsqrt(var+eps) + (be - mean*scale))
// ---------------------------------------------------------------------------

__device__ inline float bf2f(unsigned short u) {
    union { unsigned int i; float f; } v; v.i = ((unsigned int)u) << 16; return v.f;
}
__device__ inline unsigned short f2bf(float f) {
    unsigned int x = __float_as_uint(f);
    unsigned int r = (x + 0x7FFFu + ((x >> 16) & 1u)) >> 16;
    return (unsigned short)r;
}

template<typename T> __device__ inline float ld1(const T* p);
template<> __device__ inline float ld1<float>(const float* p) { return *p; }
template<> __device__ inline float ld1<unsigned short>(const unsigned short* p) { return bf2f(*p); }

template<typename T> __device__ inline float4 ld4(const T* p);
template<> __device__ inline float4 ld4<float>(const float* p) { return *(const float4*)p; }
template<> __device__ inline float4 ld4<unsigned short>(const unsigned short* p) {
    ushort4 u = *(const ushort4*)p;
    return make_float4(bf2f(u.x), bf2f(u.y), bf2f(u.z), bf2f(u.w));
}

template<typename T> __device__ inline void st4(T* p, float4 v);
template<> __device__ inline void st4<float>(float* p, float4 v) { *(float4*)p = v; }
template<> __device__ inline void st4<unsigned short>(unsigned short* p, float4 v) {
    ushort4 u; u.x = f2bf(v.x); u.y = f2bf(v.y); u.z = f2bf(v.z); u.w = f2bf(v.w);
    *(ushort4*)p = u;
}

// ---- CSR build -------------------------------------------------------------
__global__ void count_deg_i(const int* __restrict__ dst, int* __restrict__ deg, int E) {
    int i = blockIdx.x * blockDim.x + threadIdx.x;
    int stride = gridDim.x * blockDim.x;
    for (; i < E; i += stride) atomicAdd(&deg[dst[i]], 1);
}

// single block, 1024 threads: exclusive scan deg[0..N) -> rowptr[0..N]
__global__ __launch_bounds__(1024) void build_rowptr(
    const int* __restrict__ deg, int* __restrict__ rowptr, int N)
{
    __shared__ int ssum[1024];
    const int t = threadIdx.x;
    const int chunk = (N + 1023) / 1024;
    const int lo = t * chunk;
    const int hi = min(lo + chunk, N);
    int s = 0;
    for (int i = lo; i < hi; ++i) s += deg[i];
    ssum[t] = s;
    __syncthreads();
    for (int off = 1; off < 1024; off <<= 1) {
        int v = (t >= off) ? ssum[t - off] : 0;
        __syncthreads();
        ssum[t] += v;
        __syncthreads();
    }
    int run = (t == 0) ? 0 : ssum[t - 1];
    for (int i = lo; i < hi; ++i) { rowptr[i] = run; run += deg[i]; }
    if (lo < N && hi == N) rowptr[N] = run;
}

__global__ void dinv_from_rowptr(const int* __restrict__ rowptr, float* __restrict__ dinv, int N) {
    int i = blockIdx.x * blockDim.x + threadIdx.x;
    if (i < N) dinv[i] = rsqrtf((float)(rowptr[i + 1] - rowptr[i]) + 1.0f);
}

__global__ void fill_csr(const int* __restrict__ src, const int* __restrict__ dst,
                         const int* __restrict__ rowptr, int* __restrict__ cnt,
                         int* __restrict__ col, int E)
{
    int i = blockIdx.x * blockDim.x + threadIdx.x;
    int stride = gridDim.x * blockDim.x;
    for (; i < E; i += stride) {
        int d = dst[i];
        int pos = atomicAdd(&cnt[d], 1);
        col[rowptr[d] + pos] = src[i];
    }
}

// ---- SGEMM: C[M,256] = (A[M,K] @ W[K,256]) * dinv[row], 128x128 tile -------
template<typename TA, typename TC>
__global__ __launch_bounds__(256) void gemm_xs(
    const TA* __restrict__ A, const float* __restrict__ W,
    const float* __restrict__ dinv, TC* __restrict__ C, int M, int K)
{
    const int Nd = 256;
    __shared__ float As[16][132];   // As[k][m]
    __shared__ float Bs[16][128];

    const int tid = threadIdx.x;
    const int bm = blockIdx.x * 128;
    const int bn = blockIdx.y * 128;
    const int tr = (tid >> 4) << 3;
    const int tc = (tid & 15) << 3;
    const int arow = tid >> 2;
    const int acol = (tid & 3) << 2;
    const int wrow = tid >> 4;
    const int wcol = (tid & 15) << 2;

    float acc[8][8];
    #pragma unroll
    for (int i = 0; i < 8; ++i)
        #pragma unroll
        for (int j = 0; j < 8; ++j) acc[i][j] = 0.f;

    for (int k0 = 0; k0 < K; k0 += 16) {
        #pragma unroll
        for (int h = 0; h < 2; ++h) {
            int r = bm + arow + h * 64;
            float4 av = make_float4(0.f, 0.f, 0.f, 0.f);
            if (r < M) av = ld4(A + (size_t)r * K + k0 + acol);
            As[acol + 0][arow + h * 64] = av.x;
            As[acol + 1][arow + h * 64] = av.y;
            As[acol + 2][arow + h * 64] = av.z;
            As[acol + 3][arow + h * 64] = av.w;
        }
        #pragma unroll
        for (int h = 0; h < 2; ++h) {
            float4 wv = *(const float4*)(W + (size_t)(k0 + wrow) * Nd + bn + wcol + h * 64);
            *(float4*)&Bs[wrow][wcol + h * 64] = wv;
        }
        __syncthreads();
        #pragma unroll
        for (int k = 0; k < 16; ++k) {
            float4 a0 = *(const float4*)&As[k][tr];
            float4 a1 = *(const float4*)&As[k][tr + 4];
            float4 b0 = *(const float4*)&Bs[k][tc];
            float4 b1 = *(const float4*)&Bs[k][tc + 4];
            float a[8] = {a0.x, a0.y, a0.z, a0.w, a1.x, a1.y, a1.z, a1.w};
            float b[8] = {b0.x, b0.y, b0.z, b0.w, b1.x, b1.y, b1.z, b1.w};
            #pragma unroll
            for (int i = 0; i < 8; ++i)
                #pragma unroll
                for (int j = 0; j < 8; ++j)
                    acc[i][j] = fmaf(a[i], b[j], acc[i][j]);
        }
        __syncthreads();
    }
    #pragma unroll
    for (int i = 0; i < 8; ++i) {
        int r = bm + tr + i;
        if (r < M) {
            float sc = dinv[r];
            TC* cp = C + (size_t)r * Nd + bn + tc;
            st4(cp + 0, make_float4(acc[i][0] * sc, acc[i][1] * sc, acc[i][2] * sc, acc[i][3] * sc));
            st4(cp + 4, make_float4(acc[i][4] * sc, acc[i][5] * sc, acc[i][6] * sc, acc[i][7] * sc));
        }
    }
}

// ---- CSR gather + pre-BN activation + column stats (H=256) -----------------
// wave per node: t[n] = dinv[n]*(xs[n] + sum_nbr xs) + b; stats += t, t*t
template<typename TS>
__global__ __launch_bounds__(256) void gather_bn(
    const TS* __restrict__ xs, const int* __restrict__ rowptr,
    const int* __restrict__ col, const float* __restrict__ dinv,
    const float* __restrict__ b, float* __restrict__ t_out,
    float* __restrict__ stats, int N)
{
    __shared__ float lred[4][512];
    const int lane = threadIdx.x & 63;
    const int wid = threadIdx.x >> 6;
    const int c4 = lane * 4;
    const float4 bv = *(const float4*)(b + c4);

    float s0 = 0, s1 = 0, s2 = 0, s3 = 0;
    float q0 = 0, q1 = 0, q2 = 0, q3 = 0;

    int w = (blockIdx.x * blockDim.x + threadIdx.x) >> 6;
    const int nw = (gridDim.x * blockDim.x) >> 6;
    for (int n = w; n < N; n += nw) {
        const int e0 = rowptr[n], e1 = rowptr[n + 1];
        float4 acc = ld4(xs + (size_t)n * 256 + c4);   // self-loop term
        for (int e = e0; e < e1; ++e) {
            int s = col[e];
            float4 v = ld4(xs + (size_t)s * 256 + c4);
            acc.x += v.x; acc.y += v.y; acc.z += v.z; acc.w += v.w;
        }
        const float di = dinv[n];
        float4 t;
        t.x = fmaf(di, acc.x, bv.x);
        t.y = fmaf(di, acc.y, bv.y);
        t.z = fmaf(di, acc.z, bv.z);
        t.w = fmaf(di, acc.w, bv.w);
        *(float4*)(t_out + (size_t)n * 256 + c4) = t;
        s0 += t.x; s1 += t.y; s2 += t.z; s3 += t.w;
        q0 += t.x * t.x; q1 += t.y * t.y; q2 += t.z * t.z; q3 += t.w * t.w;
    }
    lred[wid][c4 + 0] = s0; lred[wid][c4 + 1] = s1;
    lred[wid][c4 + 2] = s2; lred[wid][c4 + 3] = s3;
    lred[wid][256 + c4 + 0] = q0; lred[wid][256 + c4 + 1] = q1;
    lred[wid][256 + c4 + 2] = q2; lred[wid][256 + c4 + 3] = q3;
    __syncthreads();
    for (int i = threadIdx.x; i < 512; i += 256) {
        float v = lred[0][i] + lred[1][i] + lred[2][i] + lred[3][i];
        atomicAdd(&stats[i], v);
    }
}

__global__ void bn_finalize(const float* __restrict__ stats,
                            const float* __restrict__ g, const float* __restrict__ be,
                            float* __restrict__ ss, int N)
{
    int f = threadIdx.x;
    float m = stats[f] / (float)N;
    float v = stats[256 + f] / (float)N - m * m;
    float sc = g[f] * rsqrtf(v + 1e-5f);
    ss[f] = sc;
    ss[256 + f] = be[f] - m * sc;
}

// ---- h = relu(t*scale + shift) ---------------------------------------------
template<typename TH>
__global__ __launch_bounds__(256) void bn_apply(
    const float* __restrict__ t, const float* __restrict__ ss,
    TH* __restrict__ out, int N)
{
    const float4* a4 = (const float4*)t;
    const float4* sc4 = (const float4*)ss;
    const float4* sh4 = (const float4*)(ss + 256);
    size_t total = (size_t)N * 64;
    size_t stride = (size_t)gridDim.x * blockDim.x;
    for (size_t i = blockIdx.x * (size_t)blockDim.x + threadIdx.x; i < total; i += stride) {
        int c = (int)(i & 63);
        float4 a = a4[i], s = sc4[c], h = sh4[c];
        float4 r;
        r.x = fmaxf(fmaf(a.x, s.x, h.x), 0.f);
        r.y = fmaxf(fmaf(a.y, s.y, h.y), 0.f);
        r.z = fmaxf(fmaf(a.z, s.z, h.z), 0.f);
        r.w = fmaxf(fmaf(a.w, s.w, h.w), 0.f);
        st4(out + i * 4, r);
    }
}

// ---- segment pool (batch sorted): pooled[g] = sum relu(t*sc+sh) ------------
__global__ __launch_bounds__(256) void pool_seg(
    const float* __restrict__ t, const int* __restrict__ batch,
    const float* __restrict__ ss, float* __restrict__ pooled, int N)
{
    __shared__ float lred[4][256];
    const int g = blockIdx.x;
    const int lane = threadIdx.x & 63;
    const int wid = threadIdx.x >> 6;
    const int c4 = lane * 4;

    int lo = 0, hi = N;                      // lower_bound(batch, g)
    while (lo < hi) { int m = (lo + hi) >> 1; if (batch[m] < g) lo = m + 1; else hi = m; }
    const int start = lo;
    hi = N;                                   // lower_bound(batch, g+1)
    while (lo < hi) { int m = (lo + hi) >> 1; if (batch[m] < g + 1) lo = m + 1; else hi = m; }
    const int end = lo;

    const float4 sc = *(const float4*)(ss + c4);
    const float4 sh = *(const float4*)(ss + 256 + c4);
    float4 acc = make_float4(0.f, 0.f, 0.f, 0.f);
    for (int r = start + wid; r < end; r += 4) {
        float4 a = *(const float4*)(t + (size_t)r * 256 + c4);
        acc.x += fmaxf(fmaf(a.x, sc.x, sh.x), 0.f);
        acc.y += fmaxf(fmaf(a.y, sc.y, sh.y), 0.f);
        acc.z += fmaxf(fmaf(a.z, sc.z, sh.z), 0.f);
        acc.w += fmaxf(fmaf(a.w, sc.w, sh.w), 0.f);
    }
    lred[wid][c4 + 0] = acc.x; lred[wid][c4 + 1] = acc.y;
    lred[wid][c4 + 2] = acc.z; lred[wid][c4 + 3] = acc.w;
    __syncthreads();
    int i = threadIdx.x;
    pooled[(size_t)g * 256 + i] = lred[0][i] + lred[1][i] + lred[2][i] + lred[3][i];
}

// ---- fused MLP --------------------------------------------------------------
__global__ __launch_bounds__(256) void mlp_fused(
    const float* __restrict__ pooled,
    const float* __restrict__ LW1, const float* __restrict__ Lb1,
    const float* __restrict__ LW2, const float* __restrict__ Lb2,
    float* __restrict__ out)
{
    __shared__ float sp[256];
    __shared__ float red[256];
    const int g = blockIdx.x;
    const int t = threadIdx.x;
    sp[t] = pooled[(size_t)g * 256 + t];
    __syncthreads();
    float acc = Lb1[t];
    #pragma unroll 8
    for (int k = 0; k < 256; ++k) acc = fmaf(sp[k], LW1[k * 256 + t], acc);
    acc = fmaxf(acc, 0.f);
    red[t] = acc * LW2[t];
    __syncthreads();
    for (int s = 128; s > 0; s >>= 1) {
        if (t < s) red[t] += red[t + s];
        __syncthreads();
    }
    if (t == 0) out[g] = red[0] + Lb2[0];
}

// ---- fallback: atomic scatter + separate bn_stats --------------------------
template<typename TS>
__global__ __launch_bounds__(256) void scatter_edges(
    const TS* __restrict__ xs, const int* __restrict__ src,
    const int* __restrict__ dst, float* __restrict__ agg, int E)
{
    const int lane = threadIdx.x & 63;
    int wid = (blockIdx.x * blockDim.x + threadIdx.x) >> 6;
    const int nw = (gridDim.x * blockDim.x) >> 6;
    for (int e = wid; e < E; e += nw) {
        int s = src[e], d = dst[e];
        float4 v = ld4(xs + (size_t)s * 256 + lane * 4);
        float* ap = agg + (size_t)d * 256 + lane * 4;
        atomicAdd(ap + 0, v.x);
        atomicAdd(ap + 1, v.y);
        atomicAdd(ap + 2, v.z);
        atomicAdd(ap + 3, v.w);
    }
}

template<typename TS>
__global__ __launch_bounds__(256) void bn_stats(
    float* __restrict__ agg, const TS* __restrict__ xs,
    const float* __restrict__ dinv, const float* __restrict__ b,
    float* __restrict__ stats, int N)
{
    const int f = threadIdx.x;
    const float bf = b[f];
    float sum = 0.f, sq = 0.f;
    for (int r = blockIdx.x; r < N; r += gridDim.x) {
        float di = dinv[r];
        size_t o = (size_t)r * 256 + f;
        float t = di * (agg[o] + ld1(xs + o)) + bf;
        agg[o] = t;
        sum += t;
        sq += t * t;
    }
    atomicAdd(&stats[f], sum);
    atomicAdd(&stats[256 + f], sq);
}

// ---------------------------------------------------------------------------
extern "C" void kernel_launch(void* const* d_in, const int* in_sizes, int n_in,
                              void* d_out, int out_size, void* d_ws, size_t ws_size,
                              hipStream_t stream)
{
    const float* x    = (const float*)d_in[0];
    const int*   ei   = (const int*)d_in[1];
    const int*   batch= (const int*)d_in[2];
    const float* W1 = (const float*)d_in[3];  const float* b1 = (const float*)d_in[4];
    const float* W2 = (const float*)d_in[5];  const float* b2 = (const float*)d_in[6];
    const float* W3 = (const float*)d_in[7];  const float* b3 = (const float*)d_in[8];
    const float* g1 = (const float*)d_in[9];  const float* be1= (const float*)d_in[10];
    const float* g2 = (const float*)d_in[11]; const float* be2= (const float*)d_in[12];
    const float* g3 = (const float*)d_in[13]; const float* be3= (const float*)d_in[14];
    const float* LW1= (const float*)d_in[15]; const float* Lb1= (const float*)d_in[16];
    const float* LW2= (const float*)d_in[17]; const float* Lb2= (const float*)d_in[18];

    const int N = in_sizes[2];            // 100000
    const int E = in_sizes[1] / 2;        // 300000
    const int F = in_sizes[0] / N;        // 128
    const int H = in_sizes[4];            // 256
    const int G = out_size;               // 2048
    const int* src = ei;
    const int* dst = ei + E;
    const size_t NH = (size_t)N * H;

    const float* Wl[3] = {W1, W2, W3};
    const float* bl[3] = {b1, b2, b3};
    const float* gl[3] = {g1, g2, g3};
    const float* bel[3]= {be1, be2, be3};

    // ---- workspace layout (compact bf16 storage) ----
    char* p = (char*)d_ws;
    float* AGG = (float*)p;            p += NH * 4;              // t (fp32)
    unsigned short* XS = (unsigned short*)p;  p += NH * 2;       // xs (bf16)
    unsigned short* HB = (unsigned short*)p;  p += NH * 2;       // h  (bf16)
    float* dinv = (float*)p;           p += (((size_t)N * 4) + 255) & ~(size_t)255;
    int* degi  = (int*)p;              p += (((size_t)N * 4) + 255) & ~(size_t)255;
    float* stats = (float*)p;          p += 2048;
    float* ss    = (float*)p;          p += 2048;
    float* pooled= (float*)p;          p += (size_t)G * H * 4;
    int* rowptr = (int*)p;             p += (((size_t)(N + 1) * 4) + 255) & ~(size_t)255;
    int* col    = (int*)p;             p += (size_t)E * 4;
    const size_t need_csr = (size_t)(p - (char*)d_ws);

    const bool use_csr = (ws_size >= need_csr);

    // degree / dinv (+ CSR build when it fits)
    hipMemsetAsync(degi, 0, (size_t)N * sizeof(int), stream);
    count_deg_i<<<1024, 256, 0, stream>>>(dst, degi, E);
    if (use_csr) {
        build_rowptr<<<1, 1024, 0, stream>>>(degi, rowptr, N);
        dinv_from_rowptr<<<(N + 255) / 256, 256, 0, stream>>>(rowptr, dinv, N);
        hipMemsetAsync(degi, 0, (size_t)N * sizeof(int), stream);   // reuse as fill cnt
        fill_csr<<<1024, 256, 0, stream>>>(src, dst, rowptr, degi, col, E);
    } else {
        // dinv from degi directly
        // (reuse dinv_from_rowptr shape: write rowptr-free version inline)
        // simple lambda-kernel replacement:
        // we just build rowptr anyway if space for rowptr exists? No — use scatter path.
        // compute dinv via a tiny kernel below
        struct L {};
        // fallthrough handled after kernel def
    }

    if (!use_csr) {
        // dinv[i] = rsqrt(degi[i]+1)
        // implemented via finish kernel:
        extern __global__ void finish_dinv_i(const int*, float*, int);
    }

    for (int L = 0; L < 3; ++L) {
        dim3 grid((N + 127) / 128, H / 128);
        if (L == 0)
            gemm_xs<float, unsigned short><<<grid, 256, 0, stream>>>(x, Wl[L], dinv, XS, N, F);
        else
            gemm_xs<unsigned short, unsigned short><<<grid, 256, 0, stream>>>(HB, Wl[L], dinv, XS, N, H);

        hipMemsetAsync(stats, 0, 512 * sizeof(float), stream);
        if (use_csr) {
            gather_bn<unsigned short><<<1024, 256, 0, stream>>>(
                XS, rowptr, col, dinv, bl[L], AGG, stats, N);
        } else {
            hipMemsetAsync(AGG, 0, NH * sizeof(float), stream);
            scatter_edges<unsigned short><<<4096, 256, 0, stream>>>(XS, src, dst, AGG, E);
            bn_stats<unsigned short><<<1024, 256, 0, stream>>>(AGG, XS, dinv, bl[L], stats, N);
        }
        bn_finalize<<<1, 256, 0, stream>>>(stats, gl[L], bel[L], ss, N);
        if (L < 2)
            bn_apply<unsigned short><<<2048, 256, 0, stream>>>(AGG, ss, HB, N);
        else
            pool_seg<<<G, 256, 0, stream>>>(AGG, batch, ss, pooled, N);
    }

    mlp_fused<<<G, 256, 0, stream>>>(pooled, LW1, Lb1, LW2, Lb2, (float*)d_out);
}

// fallback dinv kernel (defined after use declaration above)
__global__ void finish_dinv_i(const int* __restrict__ deg, float* __restrict__ dinv, int N) {
    int i = blockIdx.x * blockDim.x + threadIdx.x;
    if (i < N) dinv[i] = rsqrtf((float)deg[i] + 1.0f);
}

// Round 4
// 772.775 us; speedup vs baseline: 5.4783x; 1.3915x over previous
//
#include <hip/hip_runtime.h>

// ---------------------------------------------------------------------------
// GCN: 3x (GCNConv -> BatchNorm -> ReLU) -> global_add_pool -> MLP
// bf16 MFMA GEMM + CSR-gather aggregation. All activations stored bf16,
// stats/accum in fp32.
//
// Math (equal to reference up to reordering):
//   xs   = (h @ W) * dinv[row]
//   t    = dinv[n] * (xs[n] + sum_{e: dst=n} xs[src_e]) + b
//   h'   = relu(t * g*rsqrt(var+eps) + (be - mean*scale))
// ---------------------------------------------------------------------------

typedef __attribute__((ext_vector_type(8))) short bf16x8;
typedef __attribute__((ext_vector_type(4))) float f32x4;

__device__ inline float bf2f(unsigned short u) {
    union { unsigned int i; float f; } v; v.i = ((unsigned int)u) << 16; return v.f;
}
__device__ inline unsigned short f2bf(float f) {
    unsigned int x = __float_as_uint(f);
    unsigned int r = (x + 0x7FFFu + ((x >> 16) & 1u)) >> 16;
    return (unsigned short)r;
}

__device__ inline float4 ld4u(const unsigned short* p) {
    ushort4 u = *(const ushort4*)p;
    return make_float4(bf2f(u.x), bf2f(u.y), bf2f(u.z), bf2f(u.w));
}
__device__ inline void st4u(unsigned short* p, float4 v) {
    ushort4 u; u.x = f2bf(v.x); u.y = f2bf(v.y); u.z = f2bf(v.z); u.w = f2bf(v.w);
    *(ushort4*)p = u;
}

// ---- CSR build -------------------------------------------------------------
__global__ void count_deg_i(const int* __restrict__ dst, int* __restrict__ deg, int E) {
    int i = blockIdx.x * blockDim.x + threadIdx.x;
    int stride = gridDim.x * blockDim.x;
    for (; i < E; i += stride) atomicAdd(&deg[dst[i]], 1);
}

__global__ __launch_bounds__(1024) void build_rowptr(
    const int* __restrict__ deg, int* __restrict__ rowptr, int N)
{
    __shared__ int ssum[1024];
    const int t = threadIdx.x;
    const int chunk = (N + 1023) / 1024;
    const int lo = t * chunk;
    const int hi = min(lo + chunk, N);
    int s = 0;
    for (int i = lo; i < hi; ++i) s += deg[i];
    ssum[t] = s;
    __syncthreads();
    for (int off = 1; off < 1024; off <<= 1) {
        int v = (t >= off) ? ssum[t - off] : 0;
        __syncthreads();
        ssum[t] += v;
        __syncthreads();
    }
    int run = (t == 0) ? 0 : ssum[t - 1];
    for (int i = lo; i < hi; ++i) { rowptr[i] = run; run += deg[i]; }
    if (lo < N && hi == N) rowptr[N] = run;
}

__global__ void dinv_from_rowptr(const int* __restrict__ rowptr, float* __restrict__ dinv, int N) {
    int i = blockIdx.x * blockDim.x + threadIdx.x;
    if (i < N) dinv[i] = rsqrtf((float)(rowptr[i + 1] - rowptr[i]) + 1.0f);
}

__global__ void fill_csr(const int* __restrict__ src, const int* __restrict__ dst,
                         const int* __restrict__ rowptr, int* __restrict__ cnt,
                         int* __restrict__ col, int E)
{
    int i = blockIdx.x * blockDim.x + threadIdx.x;
    int stride = gridDim.x * blockDim.x;
    for (; i < E; i += stride) {
        int d = dst[i];
        int pos = atomicAdd(&cnt[d], 1);
        col[rowptr[d] + pos] = src[i];
    }
}

// ---- dtype conversions ------------------------------------------------------
__global__ void conv_bf16(const float* __restrict__ in, unsigned short* __restrict__ out,
                          size_t n4)
{
    size_t i = blockIdx.x * (size_t)blockDim.x + threadIdx.x;
    size_t stride = (size_t)gridDim.x * blockDim.x;
    const float4* in4 = (const float4*)in;
    for (; i < n4; i += stride) {
        float4 v = in4[i];
        st4u(out + i * 4, v);
    }
}

// WT[n][k] = bf16(W[k][n]),  W is [K,256]
__global__ void make_wt(const float* __restrict__ W, unsigned short* __restrict__ WT, int K) {
    int i = blockIdx.x * blockDim.x + threadIdx.x;
    if (i < K * 256) {
        int k = i >> 8, n = i & 255;
        WT[n * K + k] = f2bf(W[i]);
    }
}

// ---- bf16 MFMA GEMM: C[Mp,256] = (A[Mp,K] @ W[K,256]) * dinv[row] ----------
// A bf16 row-major [Mp,K]; WT bf16 [256,K] (W transposed). 128x128 tile, BK=32.
// 4 waves (2x2), each wave 64x64 = 4x4 fragments of 16x16x32.
// Swapped operands: a-op = WT fragment (out cols), b-op = A fragment (rows),
// so D: row_i = output col = (lane>>4)*4+reg, col_j = X row = lane&15.
__global__ __launch_bounds__(256) void gemm_mfma(
    const unsigned short* __restrict__ A,
    const unsigned short* __restrict__ WT,
    const float* __restrict__ dinv,
    unsigned short* __restrict__ C,
    int K)
{
    __shared__ unsigned short As[128 * 32];
    __shared__ unsigned short Bs[128 * 32];

    const int tid = threadIdx.x;
    const int bm = blockIdx.x * 128;
    const int bn = blockIdx.y * 128;
    const int lane = tid & 63;
    const int wid = tid >> 6;
    const int wr = wid >> 1;     // wave row (X-row tiles)
    const int wc = wid & 1;      // wave col (out-col tiles)

    const int r0 = tid >> 2;     // 0..63, staging row (set 0)
    const int cc0 = tid & 3;     // staging 16B chunk within row

    f32x4 acc[4][4];
    #pragma unroll
    for (int m = 0; m < 4; ++m)
        #pragma unroll
        for (int n = 0; n < 4; ++n)
            acc[m][n] = (f32x4){0.f, 0.f, 0.f, 0.f};

    uint4* AsV = (uint4*)As;
    uint4* BsV = (uint4*)Bs;

    for (int k0 = 0; k0 < K; k0 += 32) {
        if (k0) __syncthreads();
        // stage 128x32 bf16 tiles of A and WT; XOR chunk swizzle (cc ^ row&3)
        {
            const int gcc = (cc0 ^ (r0 & 3)) * 8;   // element offset of 16B chunk
            uint4 va0 = *(const uint4*)(A  + (size_t)(bm + r0)      * K + k0 + gcc);
            uint4 vb0 = *(const uint4*)(WT + (size_t)(bn + r0)      * K + k0 + gcc);
            uint4 va1 = *(const uint4*)(A  + (size_t)(bm + r0 + 64) * K + k0 + gcc);
            uint4 vb1 = *(const uint4*)(WT + (size_t)(bn + r0 + 64) * K + k0 + gcc);
            AsV[r0 * 4 + cc0]        = va0;
            AsV[(r0 + 64) * 4 + cc0] = va1;
            BsV[r0 * 4 + cc0]        = vb0;
            BsV[(r0 + 64) * 4 + cc0] = vb1;
        }
        __syncthreads();

        bf16x8 af[4], bfv[4];
        #pragma unroll
        for (int n = 0; n < 4; ++n) {
            int R = wc * 64 + n * 16 + (lane & 15);
            int pc = (lane >> 4) ^ (R & 3);
            af[n] = *(const bf16x8*)&Bs[R * 32 + pc * 8];
        }
        #pragma unroll
        for (int m = 0; m < 4; ++m) {
            int R = wr * 64 + m * 16 + (lane & 15);
            int pc = (lane >> 4) ^ (R & 3);
            bfv[m] = *(const bf16x8*)&As[R * 32 + pc * 8];
        }
        #pragma unroll
        for (int m = 0; m < 4; ++m)
            #pragma unroll
            for (int n = 0; n < 4; ++n)
                acc[m][n] = __builtin_amdgcn_mfma_f32_16x16x32_bf16(
                    af[n], bfv[m], acc[m][n], 0, 0, 0);
    }

    // epilogue: scale by dinv[row], pack 4 consecutive cols, store ushort4
    #pragma unroll
    for (int m = 0; m < 4; ++m) {
        int row = bm + wr * 64 + m * 16 + (lane & 15);
        float di = dinv[row];
        #pragma unroll
        for (int n = 0; n < 4; ++n) {
            int cb = bn + wc * 64 + n * 16 + ((lane >> 4) << 2);
            ushort4 u;
            u.x = f2bf(acc[m][n][0] * di);
            u.y = f2bf(acc[m][n][1] * di);
            u.z = f2bf(acc[m][n][2] * di);
            u.w = f2bf(acc[m][n][3] * di);
            *(ushort4*)(C + (size_t)row * 256 + cb) = u;
        }
    }
}

// ---- CSR gather + pre-BN activation + column stats (H=256) -----------------
__global__ __launch_bounds__(256) void gather_bn(
    const unsigned short* __restrict__ xs, const int* __restrict__ rowptr,
    const int* __restrict__ col, const float* __restrict__ dinv,
    const float* __restrict__ b, unsigned short* __restrict__ t_out,
    float* __restrict__ stats, int N)
{
    __shared__ float lred[4][512];
    const int lane = threadIdx.x & 63;
    const int wid = threadIdx.x >> 6;
    const int c4 = lane * 4;
    const float4 bv = *(const float4*)(b + c4);

    float s0 = 0, s1 = 0, s2 = 0, s3 = 0;
    float q0 = 0, q1 = 0, q2 = 0, q3 = 0;

    int w = (blockIdx.x * blockDim.x + threadIdx.x) >> 6;
    const int nw = (gridDim.x * blockDim.x) >> 6;
    for (int n = w; n < N; n += nw) {
        const int e0 = rowptr[n], e1 = rowptr[n + 1];
        float4 acc = ld4u(xs + (size_t)n * 256 + c4);   // self-loop term
        for (int e = e0; e < e1; ++e) {
            int s = col[e];
            float4 v = ld4u(xs + (size_t)s * 256 + c4);
            acc.x += v.x; acc.y += v.y; acc.z += v.z; acc.w += v.w;
        }
        const float di = dinv[n];
        float4 t;
        t.x = fmaf(di, acc.x, bv.x);
        t.y = fmaf(di, acc.y, bv.y);
        t.z = fmaf(di, acc.z, bv.z);
        t.w = fmaf(di, acc.w, bv.w);
        st4u(t_out + (size_t)n * 256 + c4, t);
        s0 += t.x; s1 += t.y; s2 += t.z; s3 += t.w;
        q0 += t.x * t.x; q1 += t.y * t.y; q2 += t.z * t.z; q3 += t.w * t.w;
    }
    lred[wid][c4 + 0] = s0; lred[wid][c4 + 1] = s1;
    lred[wid][c4 + 2] = s2; lred[wid][c4 + 3] = s3;
    lred[wid][256 + c4 + 0] = q0; lred[wid][256 + c4 + 1] = q1;
    lred[wid][256 + c4 + 2] = q2; lred[wid][256 + c4 + 3] = q3;
    __syncthreads();
    for (int i = threadIdx.x; i < 512; i += 256) {
        float v = lred[0][i] + lred[1][i] + lred[2][i] + lred[3][i];
        atomicAdd(&stats[i], v);
    }
}

__global__ void bn_finalize(const float* __restrict__ stats,
                            const float* __restrict__ g, const float* __restrict__ be,
                            float* __restrict__ ss, int N)
{
    int f = threadIdx.x;
    float m = stats[f] / (float)N;
    float v = stats[256 + f] / (float)N - m * m;
    float sc = g[f] * rsqrtf(v + 1e-5f);
    ss[f] = sc;
    ss[256 + f] = be[f] - m * sc;
}

// ---- h = relu(t*scale + shift), bf16 -> bf16 --------------------------------
__global__ __launch_bounds__(256) void bn_apply(
    const unsigned short* __restrict__ t, const float* __restrict__ ss,
    unsigned short* __restrict__ out, int N)
{
    const float4* sc4 = (const float4*)ss;
    const float4* sh4 = (const float4*)(ss + 256);
    size_t total = (size_t)N * 64;
    size_t stride = (size_t)gridDim.x * blockDim.x;
    for (size_t i = blockIdx.x * (size_t)blockDim.x + threadIdx.x; i < total; i += stride) {
        int c = (int)(i & 63);
        float4 a = ld4u(t + i * 4);
        float4 s = sc4[c], h = sh4[c];
        float4 r;
        r.x = fmaxf(fmaf(a.x, s.x, h.x), 0.f);
        r.y = fmaxf(fmaf(a.y, s.y, h.y), 0.f);
        r.z = fmaxf(fmaf(a.z, s.z, h.z), 0.f);
        r.w = fmaxf(fmaf(a.w, s.w, h.w), 0.f);
        st4u(out + i * 4, r);
    }
}

// ---- segment pool (batch sorted): pooled[g] = sum relu(t*sc+sh) ------------
__global__ __launch_bounds__(256) void pool_seg(
    const unsigned short* __restrict__ t, const int* __restrict__ batch,
    const float* __restrict__ ss, float* __restrict__ pooled, int N)
{
    __shared__ float lred[4][256];
    const int g = blockIdx.x;
    const int lane = threadIdx.x & 63;
    const int wid = threadIdx.x >> 6;
    const int c4 = lane * 4;

    int lo = 0, hi = N;
    while (lo < hi) { int m = (lo + hi) >> 1; if (batch[m] < g) lo = m + 1; else hi = m; }
    const int start = lo;
    hi = N;
    while (lo < hi) { int m = (lo + hi) >> 1; if (batch[m] < g + 1) lo = m + 1; else hi = m; }
    const int end = lo;

    const float4 sc = *(const float4*)(ss + c4);
    const float4 sh = *(const float4*)(ss + 256 + c4);
    float4 acc = make_float4(0.f, 0.f, 0.f, 0.f);
    for (int r = start + wid; r < end; r += 4) {
        float4 a = ld4u(t + (size_t)r * 256 + c4);
        acc.x += fmaxf(fmaf(a.x, sc.x, sh.x), 0.f);
        acc.y += fmaxf(fmaf(a.y, sc.y, sh.y), 0.f);
        acc.z += fmaxf(fmaf(a.z, sc.z, sh.z), 0.f);
        acc.w += fmaxf(fmaf(a.w, sc.w, sh.w), 0.f);
    }
    lred[wid][c4 + 0] = acc.x; lred[wid][c4 + 1] = acc.y;
    lred[wid][c4 + 2] = acc.z; lred[wid][c4 + 3] = acc.w;
    __syncthreads();
    int i = threadIdx.x;
    pooled[(size_t)g * 256 + i] = lred[0][i] + lred[1][i] + lred[2][i] + lred[3][i];
}

// ---- fused MLP --------------------------------------------------------------
__global__ __launch_bounds__(256) void mlp_fused(
    const float* __restrict__ pooled,
    const float* __restrict__ LW1, const float* __restrict__ Lb1,
    const float* __restrict__ LW2, const float* __restrict__ Lb2,
    float* __restrict__ out)
{
    __shared__ float sp[256];
    __shared__ float red[256];
    const int g = blockIdx.x;
    const int t = threadIdx.x;
    sp[t] = pooled[(size_t)g * 256 + t];
    __syncthreads();
    float acc = Lb1[t];
    #pragma unroll 8
    for (int k = 0; k < 256; ++k) acc = fmaf(sp[k], LW1[k * 256 + t], acc);
    acc = fmaxf(acc, 0.f);
    red[t] = acc * LW2[t];
    __syncthreads();
    for (int s = 128; s > 0; s >>= 1) {
        if (t < s) red[t] += red[t + s];
        __syncthreads();
    }
    if (t == 0) out[g] = red[0] + Lb2[0];
}

// ---------------------------------------------------------------------------
extern "C" void kernel_launch(void* const* d_in, const int* in_sizes, int n_in,
                              void* d_out, int out_size, void* d_ws, size_t ws_size,
                              hipStream_t stream)
{
    const float* x    = (const float*)d_in[0];
    const int*   ei   = (const int*)d_in[1];
    const int*   batch= (const int*)d_in[2];
    const float* W1 = (const float*)d_in[3];  const float* b1 = (const float*)d_in[4];
    const float* W2 = (const float*)d_in[5];  const float* b2 = (const float*)d_in[6];
    const float* W3 = (const float*)d_in[7];  const float* b3 = (const float*)d_in[8];
    const float* g1 = (const float*)d_in[9];  const float* be1= (const float*)d_in[10];
    const float* g2 = (const float*)d_in[11]; const float* be2= (const float*)d_in[12];
    const float* g3 = (const float*)d_in[13]; const float* be3= (const float*)d_in[14];
    const float* LW1= (const float*)d_in[15]; const float* Lb1= (const float*)d_in[16];
    const float* LW2= (const float*)d_in[17]; const float* Lb2= (const float*)d_in[18];

    const int N = in_sizes[2];            // 100000
    const int E = in_sizes[1] / 2;        // 300000
    const int F = in_sizes[0] / N;        // 128
    const int H = in_sizes[4];            // 256
    const int G = out_size;               // 2048
    const int Mp = (N + 127) & ~127;      // padded rows (100096)
    const int* src = ei;
    const int* dst = ei + E;
    const size_t NHp = (size_t)Mp * H;

    const float* Wl[3] = {W1, W2, W3};
    const float* bl[3] = {b1, b2, b3};
    const float* gl[3] = {g1, g2, g3};
    const float* bel[3]= {be1, be2, be3};

    // ---- workspace layout (all activations bf16) ----
    char* p = (char*)d_ws;
    unsigned short* TB = (unsigned short*)p;  p += NHp * 2;   // t   [Mp,256] bf16
    unsigned short* XS = (unsigned short*)p;  p += NHp * 2;   // xs  [Mp,256] bf16
    unsigned short* HB = (unsigned short*)p;  p += NHp * 2;   // h   [Mp,256] bf16 (aliases XB)
    unsigned short* XB = HB;                                  // x bf16 [Mp,128] (layer-0 only)
    float* dinv = (float*)p;           p += (((size_t)Mp * 4) + 255) & ~(size_t)255;
    int* degi  = (int*)p;              p += (((size_t)N * 4) + 255) & ~(size_t)255;
    float* stats = (float*)p;          p += 2048;
    float* ss    = (float*)p;          p += 2048;
    float* pooled= (float*)p;          p += (size_t)G * H * 4;
    int* rowptr = (int*)p;             p += (((size_t)(N + 1) * 4) + 255) & ~(size_t)255;
    int* col    = (int*)p;             p += (((size_t)E * 4) + 255) & ~(size_t)255;
    unsigned short* WTb = (unsigned short*)p;  p += (size_t)H * H * 2;

    // CSR build + dinv
    hipMemsetAsync(degi, 0, (size_t)N * sizeof(int), stream);
    count_deg_i<<<1024, 256, 0, stream>>>(dst, degi, E);
    build_rowptr<<<1, 1024, 0, stream>>>(degi, rowptr, N);
    dinv_from_rowptr<<<(N + 255) / 256, 256, 0, stream>>>(rowptr, dinv, N);
    hipMemsetAsync(degi, 0, (size_t)N * sizeof(int), stream);
    fill_csr<<<1024, 256, 0, stream>>>(src, dst, rowptr, degi, col, E);

    // x -> bf16
    conv_bf16<<<2048, 256, 0, stream>>>(x, XB, (size_t)N * F / 4);

    for (int L = 0; L < 3; ++L) {
        const int K = (L == 0) ? F : H;
        make_wt<<<(K * 256 + 255) / 256, 256, 0, stream>>>(Wl[L], WTb, K);
        dim3 grid(Mp / 128, H / 128);
        gemm_mfma<<<grid, 256, 0, stream>>>((L == 0) ? XB : HB, WTb, dinv, XS, K);
        hipMemsetAsync(stats, 0, 512 * sizeof(float), stream);
        gather_bn<<<1024, 256, 0, stream>>>(XS, rowptr, col, dinv, bl[L], TB, stats, N);
        bn_finalize<<<1, 256, 0, stream>>>(stats, gl[L], bel[L], ss, N);
        if (L < 2)
            bn_apply<<<2048, 256, 0, stream>>>(TB, ss, HB, N);
        else
            pool_seg<<<G, 256, 0, stream>>>(TB, batch, ss, pooled, N);
    }

    mlp_fused<<<G, 256, 0, stream>>>(pooled, LW1, Lb1, LW2, Lb2, (float*)d_out);
}

// Round 5
// 622.985 us; speedup vs baseline: 6.7955x; 1.2404x over previous
//
#include <hip/hip_runtime.h>

// ---------------------------------------------------------------------------
// GCN: 3x (GCNConv -> BatchNorm -> ReLU) -> global_add_pool -> MLP
// bf16 MFMA GEMM + CSR-gather aggregation. All activations stored bf16,
// stats/accum in fp32. Multi-block CSR rowptr scan.
//
// Math (equal to reference up to reordering):
//   xs   = (h @ W) * dinv[row]
//   t    = dinv[n] * (xs[n] + sum_{e: dst=n} xs[src_e]) + b
//   h'   = relu(t * g*rsqrt(var+eps) + (be - mean*scale))
// ---------------------------------------------------------------------------

typedef __attribute__((ext_vector_type(8))) short bf16x8;
typedef __attribute__((ext_vector_type(4))) float f32x4;

__device__ inline float bf2f(unsigned short u) {
    union { unsigned int i; float f; } v; v.i = ((unsigned int)u) << 16; return v.f;
}
__device__ inline unsigned short f2bf(float f) {
    unsigned int x = __float_as_uint(f);
    unsigned int r = (x + 0x7FFFu + ((x >> 16) & 1u)) >> 16;
    return (unsigned short)r;
}

__device__ inline float4 ld4u(const unsigned short* p) {
    ushort4 u = *(const ushort4*)p;
    return make_float4(bf2f(u.x), bf2f(u.y), bf2f(u.z), bf2f(u.w));
}
__device__ inline void st4u(unsigned short* p, float4 v) {
    ushort4 u; u.x = f2bf(v.x); u.y = f2bf(v.y); u.z = f2bf(v.z); u.w = f2bf(v.w);
    *(ushort4*)p = u;
}

// ---- CSR build -------------------------------------------------------------
__global__ void count_deg_i(const int* __restrict__ dst, int* __restrict__ deg, int E) {
    int i = blockIdx.x * blockDim.x + threadIdx.x;
    int stride = gridDim.x * blockDim.x;
    for (; i < E; i += stride) atomicAdd(&deg[dst[i]], 1);
}

// block b sums deg[b*512 .. b*512+512) -> psum[b]
__global__ __launch_bounds__(256) void scan_partial(
    const int* __restrict__ deg, int* __restrict__ psum, int N)
{
    __shared__ int red[256];
    const int t = threadIdx.x;
    const int i0 = blockIdx.x * 512 + t * 2;
    int s = 0;
    if (i0 < N) s += deg[i0];
    if (i0 + 1 < N) s += deg[i0 + 1];
    red[t] = s;
    __syncthreads();
    for (int off = 128; off > 0; off >>= 1) {
        if (t < off) red[t] += red[t + off];
        __syncthreads();
    }
    if (t == 0) psum[blockIdx.x] = red[0];
}

// 1 block: exclusive-scan psum[0..NB) -> poff; rowptr[N] = total
__global__ __launch_bounds__(1024) void scan_offsets(
    const int* __restrict__ psum, int* __restrict__ poff, int NB,
    int* __restrict__ rowptr, int N)
{
    __shared__ int s[1024];
    const int t = threadIdx.x;
    int v = (t < NB) ? psum[t] : 0;
    s[t] = v;
    __syncthreads();
    for (int off = 1; off < 1024; off <<= 1) {
        int u = (t >= off) ? s[t - off] : 0;
        __syncthreads();
        s[t] += u;
        __syncthreads();
    }
    if (t < NB) poff[t] = s[t] - v;
    if (t == 1023) rowptr[N] = s[1023];
}

// block b: intra-chunk exclusive scan + poff[b] -> rowptr
__global__ __launch_bounds__(256) void write_rowptr(
    const int* __restrict__ deg, const int* __restrict__ poff,
    int* __restrict__ rowptr, int N)
{
    __shared__ int s[256];
    const int t = threadIdx.x;
    const int i0 = blockIdx.x * 512 + t * 2;
    int e0 = (i0 < N) ? deg[i0] : 0;
    int e1 = (i0 + 1 < N) ? deg[i0 + 1] : 0;
    int sum = e0 + e1;
    s[t] = sum;
    __syncthreads();
    for (int off = 1; off < 256; off <<= 1) {
        int u = (t >= off) ? s[t - off] : 0;
        __syncthreads();
        s[t] += u;
        __syncthreads();
    }
    int excl = s[t] - sum + poff[blockIdx.x];
    if (i0 < N) rowptr[i0] = excl;
    if (i0 + 1 < N) rowptr[i0 + 1] = excl + e0;
}

__global__ void dinv_from_rowptr(const int* __restrict__ rowptr, float* __restrict__ dinv, int N) {
    int i = blockIdx.x * blockDim.x + threadIdx.x;
    if (i < N) dinv[i] = rsqrtf((float)(rowptr[i + 1] - rowptr[i]) + 1.0f);
}

__global__ void fill_csr(const int* __restrict__ src, const int* __restrict__ dst,
                         const int* __restrict__ rowptr, int* __restrict__ cnt,
                         int* __restrict__ col, int E)
{
    int i = blockIdx.x * blockDim.x + threadIdx.x;
    int stride = gridDim.x * blockDim.x;
    for (; i < E; i += stride) {
        int d = dst[i];
        int pos = atomicAdd(&cnt[d], 1);
        col[rowptr[d] + pos] = src[i];
    }
}

// ---- dtype conversions ------------------------------------------------------
__global__ void conv_bf16(const float* __restrict__ in, unsigned short* __restrict__ out,
                          size_t n4)
{
    size_t i = blockIdx.x * (size_t)blockDim.x + threadIdx.x;
    size_t stride = (size_t)gridDim.x * blockDim.x;
    const float4* in4 = (const float4*)in;
    for (; i < n4; i += stride) {
        float4 v = in4[i];
        st4u(out + i * 4, v);
    }
}

// WT[n][k] = bf16(W[k][n]),  W is [K,256]
__global__ void make_wt(const float* __restrict__ W, unsigned short* __restrict__ WT, int K) {
    int i = blockIdx.x * blockDim.x + threadIdx.x;
    if (i < K * 256) {
        int k = i >> 8, n = i & 255;
        WT[n * K + k] = f2bf(W[i]);
    }
}

// ---- bf16 MFMA GEMM: C[Mp,256] = (A[Mp,K] @ W[K,256]) * dinv[row] ----------
__global__ __launch_bounds__(256) void gemm_mfma(
    const unsigned short* __restrict__ A,
    const unsigned short* __restrict__ WT,
    const float* __restrict__ dinv,
    unsigned short* __restrict__ C,
    int K)
{
    __shared__ unsigned short As[128 * 32];
    __shared__ unsigned short Bs[128 * 32];

    const int tid = threadIdx.x;
    const int bm = blockIdx.x * 128;
    const int bn = blockIdx.y * 128;
    const int lane = tid & 63;
    const int wid = tid >> 6;
    const int wr = wid >> 1;
    const int wc = wid & 1;

    const int r0 = tid >> 2;
    const int cc0 = tid & 3;

    f32x4 acc[4][4];
    #pragma unroll
    for (int m = 0; m < 4; ++m)
        #pragma unroll
        for (int n = 0; n < 4; ++n)
            acc[m][n] = (f32x4){0.f, 0.f, 0.f, 0.f};

    uint4* AsV = (uint4*)As;
    uint4* BsV = (uint4*)Bs;

    for (int k0 = 0; k0 < K; k0 += 32) {
        if (k0) __syncthreads();
        {
            const int gcc = (cc0 ^ (r0 & 3)) * 8;
            uint4 va0 = *(const uint4*)(A  + (size_t)(bm + r0)      * K + k0 + gcc);
            uint4 vb0 = *(const uint4*)(WT + (size_t)(bn + r0)      * K + k0 + gcc);
            uint4 va1 = *(const uint4*)(A  + (size_t)(bm + r0 + 64) * K + k0 + gcc);
            uint4 vb1 = *(const uint4*)(WT + (size_t)(bn + r0 + 64) * K + k0 + gcc);
            AsV[r0 * 4 + cc0]        = va0;
            AsV[(r0 + 64) * 4 + cc0] = va1;
            BsV[r0 * 4 + cc0]        = vb0;
            BsV[(r0 + 64) * 4 + cc0] = vb1;
        }
        __syncthreads();

        bf16x8 af[4], bfv[4];
        #pragma unroll
        for (int n = 0; n < 4; ++n) {
            int R = wc * 64 + n * 16 + (lane & 15);
            int pc = (lane >> 4) ^ (R & 3);
            af[n] = *(const bf16x8*)&Bs[R * 32 + pc * 8];
        }
        #pragma unroll
        for (int m = 0; m < 4; ++m) {
            int R = wr * 64 + m * 16 + (lane & 15);
            int pc = (lane >> 4) ^ (R & 3);
            bfv[m] = *(const bf16x8*)&As[R * 32 + pc * 8];
        }
        #pragma unroll
        for (int m = 0; m < 4; ++m)
            #pragma unroll
            for (int n = 0; n < 4; ++n)
                acc[m][n] = __builtin_amdgcn_mfma_f32_16x16x32_bf16(
                    af[n], bfv[m], acc[m][n], 0, 0, 0);
    }

    #pragma unroll
    for (int m = 0; m < 4; ++m) {
        int row = bm + wr * 64 + m * 16 + (lane & 15);
        float di = dinv[row];
        #pragma unroll
        for (int n = 0; n < 4; ++n) {
            int cb = bn + wc * 64 + n * 16 + ((lane >> 4) << 2);
            ushort4 u;
            u.x = f2bf(acc[m][n][0] * di);
            u.y = f2bf(acc[m][n][1] * di);
            u.z = f2bf(acc[m][n][2] * di);
            u.w = f2bf(acc[m][n][3] * di);
            *(ushort4*)(C + (size_t)row * 256 + cb) = u;
        }
    }
}

// ---- CSR gather + pre-BN activation + column stats (H=256) -----------------
__global__ __launch_bounds__(256) void gather_bn(
    const unsigned short* __restrict__ xs, const int* __restrict__ rowptr,
    const int* __restrict__ col, const float* __restrict__ dinv,
    const float* __restrict__ b, unsigned short* __restrict__ t_out,
    float* __restrict__ stats, int N)
{
    __shared__ float lred[4][512];
    const int lane = threadIdx.x & 63;
    const int wid = threadIdx.x >> 6;
    const int c4 = lane * 4;
    const float4 bv = *(const float4*)(b + c4);

    float s0 = 0, s1 = 0, s2 = 0, s3 = 0;
    float q0 = 0, q1 = 0, q2 = 0, q3 = 0;

    int w = (blockIdx.x * blockDim.x + threadIdx.x) >> 6;
    const int nw = (gridDim.x * blockDim.x) >> 6;
    for (int n = w; n < N; n += nw) {
        const int e0 = rowptr[n], e1 = rowptr[n + 1];
        float4 acc = ld4u(xs + (size_t)n * 256 + c4);
        for (int e = e0; e < e1; ++e) {
            int s = col[e];
            float4 v = ld4u(xs + (size_t)s * 256 + c4);
            acc.x += v.x; acc.y += v.y; acc.z += v.z; acc.w += v.w;
        }
        const float di = dinv[n];
        float4 t;
        t.x = fmaf(di, acc.x, bv.x);
        t.y = fmaf(di, acc.y, bv.y);
        t.z = fmaf(di, acc.z, bv.z);
        t.w = fmaf(di, acc.w, bv.w);
        st4u(t_out + (size_t)n * 256 + c4, t);
        s0 += t.x; s1 += t.y; s2 += t.z; s3 += t.w;
        q0 += t.x * t.x; q1 += t.y * t.y; q2 += t.z * t.z; q3 += t.w * t.w;
    }
    lred[wid][c4 + 0] = s0; lred[wid][c4 + 1] = s1;
    lred[wid][c4 + 2] = s2; lred[wid][c4 + 3] = s3;
    lred[wid][256 + c4 + 0] = q0; lred[wid][256 + c4 + 1] = q1;
    lred[wid][256 + c4 + 2] = q2; lred[wid][256 + c4 + 3] = q3;
    __syncthreads();
    for (int i = threadIdx.x; i < 512; i += 256) {
        float v = lred[0][i] + lred[1][i] + lred[2][i] + lred[3][i];
        atomicAdd(&stats[i], v);
    }
}

__global__ void bn_finalize(const float* __restrict__ stats,
                            const float* __restrict__ g, const float* __restrict__ be,
                            float* __restrict__ ss, int N)
{
    int f = threadIdx.x;
    float m = stats[f] / (float)N;
    float v = stats[256 + f] / (float)N - m * m;
    float sc = g[f] * rsqrtf(v + 1e-5f);
    ss[f] = sc;
    ss[256 + f] = be[f] - m * sc;
}

// ---- h = relu(t*scale + shift), bf16 -> bf16 --------------------------------
__global__ __launch_bounds__(256) void bn_apply(
    const unsigned short* __restrict__ t, const float* __restrict__ ss,
    unsigned short* __restrict__ out, int N)
{
    const float4* sc4 = (const float4*)ss;
    const float4* sh4 = (const float4*)(ss + 256);
    size_t total = (size_t)N * 64;
    size_t stride = (size_t)gridDim.x * blockDim.x;
    for (size_t i = blockIdx.x * (size_t)blockDim.x + threadIdx.x; i < total; i += stride) {
        int c = (int)(i & 63);
        float4 a = ld4u(t + i * 4);
        float4 s = sc4[c], h = sh4[c];
        float4 r;
        r.x = fmaxf(fmaf(a.x, s.x, h.x), 0.f);
        r.y = fmaxf(fmaf(a.y, s.y, h.y), 0.f);
        r.z = fmaxf(fmaf(a.z, s.z, h.z), 0.f);
        r.w = fmaxf(fmaf(a.w, s.w, h.w), 0.f);
        st4u(out + i * 4, r);
    }
}

// ---- segment pool (batch sorted): pooled[g] = sum relu(t*sc+sh) ------------
__global__ __launch_bounds__(256) void pool_seg(
    const unsigned short* __restrict__ t, const int* __restrict__ batch,
    const float* __restrict__ ss, float* __restrict__ pooled, int N)
{
    __shared__ float lred[4][256];
    const int g = blockIdx.x;
    const int lane = threadIdx.x & 63;
    const int wid = threadIdx.x >> 6;
    const int c4 = lane * 4;

    int lo = 0, hi = N;
    while (lo < hi) { int m = (lo + hi) >> 1; if (batch[m] < g) lo = m + 1; else hi = m; }
    const int start = lo;
    hi = N;
    while (lo < hi) { int m = (lo + hi) >> 1; if (batch[m] < g + 1) lo = m + 1; else hi = m; }
    const int end = lo;

    const float4 sc = *(const float4*)(ss + c4);
    const float4 sh = *(const float4*)(ss + 256 + c4);
    float4 acc = make_float4(0.f, 0.f, 0.f, 0.f);
    for (int r = start + wid; r < end; r += 4) {
        float4 a = ld4u(t + (size_t)r * 256 + c4);
        acc.x += fmaxf(fmaf(a.x, sc.x, sh.x), 0.f);
        acc.y += fmaxf(fmaf(a.y, sc.y, sh.y), 0.f);
        acc.z += fmaxf(fmaf(a.z, sc.z, sh.z), 0.f);
        acc.w += fmaxf(fmaf(a.w, sc.w, sh.w), 0.f);
    }
    lred[wid][c4 + 0] = acc.x; lred[wid][c4 + 1] = acc.y;
    lred[wid][c4 + 2] = acc.z; lred[wid][c4 + 3] = acc.w;
    __syncthreads();
    int i = threadIdx.x;
    pooled[(size_t)g * 256 + i] = lred[0][i] + lred[1][i] + lred[2][i] + lred[3][i];
}

// ---- fused MLP --------------------------------------------------------------
__global__ __launch_bounds__(256) void mlp_fused(
    const float* __restrict__ pooled,
    const float* __restrict__ LW1, const float* __restrict__ Lb1,
    const float* __restrict__ LW2, const float* __restrict__ Lb2,
    float* __restrict__ out)
{
    __shared__ float sp[256];
    __shared__ float red[256];
    const int g = blockIdx.x;
    const int t = threadIdx.x;
    sp[t] = pooled[(size_t)g * 256 + t];
    __syncthreads();
    float acc = Lb1[t];
    #pragma unroll 8
    for (int k = 0; k < 256; ++k) acc = fmaf(sp[k], LW1[k * 256 + t], acc);
    acc = fmaxf(acc, 0.f);
    red[t] = acc * LW2[t];
    __syncthreads();
    for (int s = 128; s > 0; s >>= 1) {
        if (t < s) red[t] += red[t + s];
        __syncthreads();
    }
    if (t == 0) out[g] = red[0] + Lb2[0];
}

// ---------------------------------------------------------------------------
extern "C" void kernel_launch(void* const* d_in, const int* in_sizes, int n_in,
                              void* d_out, int out_size, void* d_ws, size_t ws_size,
                              hipStream_t stream)
{
    const float* x    = (const float*)d_in[0];
    const int*   ei   = (const int*)d_in[1];
    const int*   batch= (const int*)d_in[2];
    const float* W1 = (const float*)d_in[3];  const float* b1 = (const float*)d_in[4];
    const float* W2 = (const float*)d_in[5];  const float* b2 = (const float*)d_in[6];
    const float* W3 = (const float*)d_in[7];  const float* b3 = (const float*)d_in[8];
    const float* g1 = (const float*)d_in[9];  const float* be1= (const float*)d_in[10];
    const float* g2 = (const float*)d_in[11]; const float* be2= (const float*)d_in[12];
    const float* g3 = (const float*)d_in[13]; const float* be3= (const float*)d_in[14];
    const float* LW1= (const float*)d_in[15]; const float* Lb1= (const float*)d_in[16];
    const float* LW2= (const float*)d_in[17]; const float* Lb2= (const float*)d_in[18];

    const int N = in_sizes[2];            // 100000
    const int E = in_sizes[1] / 2;        // 300000
    const int F = in_sizes[0] / N;        // 128
    const int H = in_sizes[4];            // 256
    const int G = out_size;               // 2048
    const int Mp = (N + 127) & ~127;      // padded rows
    const int NB = (N + 511) / 512;       // scan chunks
    const int* src = ei;
    const int* dst = ei + E;
    const size_t NHp = (size_t)Mp * H;

    const float* Wl[3] = {W1, W2, W3};
    const float* bl[3] = {b1, b2, b3};
    const float* gl[3] = {g1, g2, g3};
    const float* bel[3]= {be1, be2, be3};

    // ---- workspace layout ----
    char* p = (char*)d_ws;
    unsigned short* TB = (unsigned short*)p;  p += NHp * 2;   // t   [Mp,256] bf16
    unsigned short* XS = (unsigned short*)p;  p += NHp * 2;   // xs  [Mp,256] bf16
    unsigned short* HB = (unsigned short*)p;  p += NHp * 2;   // h   [Mp,256] bf16
    unsigned short* XB = HB;                                  // x bf16 (layer-0 only)
    float* dinv = (float*)p;           p += (((size_t)Mp * 4) + 255) & ~(size_t)255;
    int* degi  = (int*)p;              p += (((size_t)N * 4) + 255) & ~(size_t)255;
    float* stats = (float*)p;          p += 2048;
    float* ss    = (float*)p;          p += 2048;
    int* psum   = (int*)p;             p += 4096;
    int* poff   = (int*)p;             p += 4096;
    float* pooled= (float*)p;          p += (size_t)G * H * 4;
    int* rowptr = (int*)p;             p += (((size_t)(N + 1) * 4) + 255) & ~(size_t)255;
    int* col    = (int*)p;             p += (((size_t)E * 4) + 255) & ~(size_t)255;
    unsigned short* WTb = (unsigned short*)p;  p += (size_t)H * H * 2;

    // CSR build + dinv (parallel scan)
    hipMemsetAsync(degi, 0, (size_t)N * sizeof(int), stream);
    count_deg_i<<<1024, 256, 0, stream>>>(dst, degi, E);
    scan_partial<<<NB, 256, 0, stream>>>(degi, psum, N);
    scan_offsets<<<1, 1024, 0, stream>>>(psum, poff, NB, rowptr, N);
    write_rowptr<<<NB, 256, 0, stream>>>(degi, poff, rowptr, N);
    dinv_from_rowptr<<<(N + 255) / 256, 256, 0, stream>>>(rowptr, dinv, N);
    hipMemsetAsync(degi, 0, (size_t)N * sizeof(int), stream);
    fill_csr<<<1024, 256, 0, stream>>>(src, dst, rowptr, degi, col, E);

    // x -> bf16
    conv_bf16<<<2048, 256, 0, stream>>>(x, XB, (size_t)N * F / 4);

    for (int L = 0; L < 3; ++L) {
        const int K = (L == 0) ? F : H;
        make_wt<<<(K * 256 + 255) / 256, 256, 0, stream>>>(Wl[L], WTb, K);
        dim3 grid(Mp / 128, H / 128);
        gemm_mfma<<<grid, 256, 0, stream>>>((L == 0) ? XB : HB, WTb, dinv, XS, K);
        hipMemsetAsync(stats, 0, 512 * sizeof(float), stream);
        gather_bn<<<1024, 256, 0, stream>>>(XS, rowptr, col, dinv, bl[L], TB, stats, N);
        bn_finalize<<<1, 256, 0, stream>>>(stats, gl[L], bel[L], ss, N);
        if (L < 2)
            bn_apply<<<2048, 256, 0, stream>>>(TB, ss, HB, N);
        else
            pool_seg<<<G, 256, 0, stream>>>(TB, batch, ss, pooled, N);
    }

    mlp_fused<<<G, 256, 0, stream>>>(pooled, LW1, Lb1, LW2, Lb2, (float*)d_out);
}

// Round 9
// 594.016 us; speedup vs baseline: 7.1270x; 1.0488x over previous
//
#include <hip/hip_runtime.h>

// ---------------------------------------------------------------------------
// GCN: 3x (GCNConv -> BatchNorm -> ReLU) -> global_add_pool -> MLP
// bf16 MFMA GEMM (BN+ReLU of previous layer fused into A-staging) +
// ILP-4 CSR-gather aggregation. Activations bf16, stats fp32.
//
// Math (equal to reference up to reordering):
//   xs   = (relu(t_prev*sc+sh) @ W) * dinv[row]     (BN fused in staging)
//   t    = dinv[n] * (xs[n] + sum_{e: dst=n} xs[src_e]) + b
// ---------------------------------------------------------------------------

typedef __attribute__((ext_vector_type(8))) short bf16x8;
typedef __attribute__((ext_vector_type(4))) float f32x4;

__device__ inline float bf2f(unsigned short u) {
    union { unsigned int i; float f; } v; v.i = ((unsigned int)u) << 16; return v.f;
}
__device__ inline unsigned short f2bf(float f) {
    unsigned int x = __float_as_uint(f);
    unsigned int r = (x + 0x7FFFu + ((x >> 16) & 1u)) >> 16;
    return (unsigned short)r;
}

__device__ inline float4 ld4u(const unsigned short* p) {
    ushort4 u = *(const ushort4*)(p);
    return make_float4(bf2f(u.x), bf2f(u.y), bf2f(u.z), bf2f(u.w));
}
__device__ inline void st4u(unsigned short* p, float4 v) {
    ushort4 u; u.x = f2bf(v.x); u.y = f2bf(v.y); u.z = f2bf(v.z); u.w = f2bf(v.w);
    *(ushort4*)p = u;
}

// ---- CSR build -------------------------------------------------------------
__global__ void count_deg_i(const int* __restrict__ dst, int* __restrict__ deg, int E) {
    int i = blockIdx.x * blockDim.x + threadIdx.x;
    int stride = gridDim.x * blockDim.x;
    for (; i < E; i += stride) atomicAdd(&deg[dst[i]], 1);
}

__global__ __launch_bounds__(256) void scan_partial(
    const int* __restrict__ deg, int* __restrict__ psum, int N)
{
    __shared__ int red[256];
    const int t = threadIdx.x;
    const int i0 = blockIdx.x * 512 + t * 2;
    int s = 0;
    if (i0 < N) s += deg[i0];
    if (i0 + 1 < N) s += deg[i0 + 1];
    red[t] = s;
    __syncthreads();
    for (int off = 128; off > 0; off >>= 1) {
        if (t < off) red[t] += red[t + off];
        __syncthreads();
    }
    if (t == 0) psum[blockIdx.x] = red[0];
}

__global__ __launch_bounds__(1024) void scan_offsets(
    const int* __restrict__ psum, int* __restrict__ poff, int NB,
    int* __restrict__ rowptr, int N)
{
    __shared__ int s[1024];
    const int t = threadIdx.x;
    int v = (t < NB) ? psum[t] : 0;
    s[t] = v;
    __syncthreads();
    for (int off = 1; off < 1024; off <<= 1) {
        int u = (t >= off) ? s[t - off] : 0;
        __syncthreads();
        s[t] += u;
        __syncthreads();
    }
    if (t < NB) poff[t] = s[t] - v;
    if (t == 1023) rowptr[N] = s[1023];
}

__global__ __launch_bounds__(256) void write_rowptr(
    const int* __restrict__ deg, const int* __restrict__ poff,
    int* __restrict__ rowptr, int N)
{
    __shared__ int s[256];
    const int t = threadIdx.x;
    const int i0 = blockIdx.x * 512 + t * 2;
    int e0 = (i0 < N) ? deg[i0] : 0;
    int e1 = (i0 + 1 < N) ? deg[i0 + 1] : 0;
    int sum = e0 + e1;
    s[t] = sum;
    __syncthreads();
    for (int off = 1; off < 256; off <<= 1) {
        int u = (t >= off) ? s[t - off] : 0;
        __syncthreads();
        s[t] += u;
        __syncthreads();
    }
    int excl = s[t] - sum + poff[blockIdx.x];
    if (i0 < N) rowptr[i0] = excl;
    if (i0 + 1 < N) rowptr[i0 + 1] = excl + e0;
}

__global__ void dinv_from_rowptr(const int* __restrict__ rowptr, float* __restrict__ dinv, int N) {
    int i = blockIdx.x * blockDim.x + threadIdx.x;
    if (i < N) dinv[i] = rsqrtf((float)(rowptr[i + 1] - rowptr[i]) + 1.0f);
}

__global__ void fill_csr(const int* __restrict__ src, const int* __restrict__ dst,
                         const int* __restrict__ rowptr, int* __restrict__ cnt,
                         int* __restrict__ col, int E)
{
    int i = blockIdx.x * blockDim.x + threadIdx.x;
    int stride = gridDim.x * blockDim.x;
    for (; i < E; i += stride) {
        int d = dst[i];
        int pos = atomicAdd(&cnt[d], 1);
        col[rowptr[d] + pos] = src[i];
    }
}

// ---- dtype conversions ------------------------------------------------------
__global__ void conv_bf16(const float* __restrict__ in, unsigned short* __restrict__ out,
                          size_t n4)
{
    size_t i = blockIdx.x * (size_t)blockDim.x + threadIdx.x;
    size_t stride = (size_t)gridDim.x * blockDim.x;
    const float4* in4 = (const float4*)in;
    for (; i < n4; i += stride) {
        float4 v = in4[i];
        st4u(out + i * 4, v);
    }
}

__global__ void make_wt(const float* __restrict__ W, unsigned short* __restrict__ WT, int K) {
    int i = blockIdx.x * blockDim.x + threadIdx.x;
    if (i < K * 256) {
        int k = i >> 8, n = i & 255;
        WT[n * K + k] = f2bf(W[i]);
    }
}

// ---- fused BN helper: 8 bf16 -> relu(v*sc+sh) -> 8 bf16 --------------------
__device__ inline unsigned int bn2(unsigned int w, float sL, float hL, float sH, float hH) {
    float lo = bf2f((unsigned short)(w & 0xFFFFu));
    float hi = bf2f((unsigned short)(w >> 16));
    lo = fmaxf(fmaf(lo, sL, hL), 0.f);
    hi = fmaxf(fmaf(hi, sH, hH), 0.f);
    return (unsigned int)f2bf(lo) | ((unsigned int)f2bf(hi) << 16);
}
__device__ inline uint4 bn8(uint4 v, const float* __restrict__ ss, int c) {
    float4 sA = *(const float4*)(ss + c);
    float4 sB = *(const float4*)(ss + c + 4);
    float4 hA = *(const float4*)(ss + 256 + c);
    float4 hB = *(const float4*)(ss + 256 + c + 4);
    uint4 r;
    r.x = bn2(v.x, sA.x, hA.x, sA.y, hA.y);
    r.y = bn2(v.y, sA.z, hA.z, sA.w, hA.w);
    r.z = bn2(v.z, sB.x, hB.x, sB.y, hB.y);
    r.w = bn2(v.w, sB.z, hB.z, sB.w, hB.w);
    return r;
}

// ---- bf16 MFMA GEMM: C[Mp,256] = (bn(A)[Mp,K] @ W[K,256]) * dinv[row] ------
template<int FUSE_BN>
__global__ __launch_bounds__(256) void gemm_mfma(
    const unsigned short* __restrict__ A,
    const unsigned short* __restrict__ WT,
    const float* __restrict__ dinv,
    const float* __restrict__ ss,
    unsigned short* __restrict__ C,
    int K)
{
    __shared__ unsigned short As[128 * 32];
    __shared__ unsigned short Bs[128 * 32];

    const int tid = threadIdx.x;
    const int bm = blockIdx.x * 128;
    const int bn = blockIdx.y * 128;
    const int lane = tid & 63;
    const int wid = tid >> 6;
    const int wr = wid >> 1;
    const int wc = wid & 1;

    const int r0 = tid >> 2;
    const int cc0 = tid & 3;

    f32x4 acc[4][4];
    #pragma unroll
    for (int m = 0; m < 4; ++m)
        #pragma unroll
        for (int n = 0; n < 4; ++n)
            acc[m][n] = (f32x4){0.f, 0.f, 0.f, 0.f};

    uint4* AsV = (uint4*)As;
    uint4* BsV = (uint4*)Bs;

    for (int k0 = 0; k0 < K; k0 += 32) {
        if (k0) __syncthreads();
        {
            const int gcc = (cc0 ^ (r0 & 3)) * 8;
            uint4 va0 = *(const uint4*)(A  + (size_t)(bm + r0)      * K + k0 + gcc);
            uint4 vb0 = *(const uint4*)(WT + (size_t)(bn + r0)      * K + k0 + gcc);
            uint4 va1 = *(const uint4*)(A  + (size_t)(bm + r0 + 64) * K + k0 + gcc);
            uint4 vb1 = *(const uint4*)(WT + (size_t)(bn + r0 + 64) * K + k0 + gcc);
            if (FUSE_BN) {
                va0 = bn8(va0, ss, k0 + gcc);
                va1 = bn8(va1, ss, k0 + gcc);
            }
            AsV[r0 * 4 + cc0]        = va0;
            AsV[(r0 + 64) * 4 + cc0] = va1;
            BsV[r0 * 4 + cc0]        = vb0;
            BsV[(r0 + 64) * 4 + cc0] = vb1;
        }
        __syncthreads();

        bf16x8 af[4], bfv[4];
        #pragma unroll
        for (int n = 0; n < 4; ++n) {
            int R = wc * 64 + n * 16 + (lane & 15);
            int pc = (lane >> 4) ^ (R & 3);
            af[n] = *(const bf16x8*)&Bs[R * 32 + pc * 8];
        }
        #pragma unroll
        for (int m = 0; m < 4; ++m) {
            int R = wr * 64 + m * 16 + (lane & 15);
            int pc = (lane >> 4) ^ (R & 3);
            bfv[m] = *(const bf16x8*)&As[R * 32 + pc * 8];
        }
        #pragma unroll
        for (int m = 0; m < 4; ++m)
            #pragma unroll
            for (int n = 0; n < 4; ++n)
                acc[m][n] = __builtin_amdgcn_mfma_f32_16x16x32_bf16(
                    af[n], bfv[m], acc[m][n], 0, 0, 0);
    }

    #pragma unroll
    for (int m = 0; m < 4; ++m) {
        int row = bm + wr * 64 + m * 16 + (lane & 15);
        float di = dinv[row];
        #pragma unroll
        for (int n = 0; n < 4; ++n) {
            int cb = bn + wc * 64 + n * 16 + ((lane >> 4) << 2);
            ushort4 u;
            u.x = f2bf(acc[m][n][0] * di);
            u.y = f2bf(acc[m][n][1] * di);
            u.z = f2bf(acc[m][n][2] * di);
            u.w = f2bf(acc[m][n][3] * di);
            *(ushort4*)(C + (size_t)row * 256 + cb) = u;
        }
    }
}

// ---- ILP-4 CSR gather + pre-BN activation + column stats (H=256) -----------
__global__ __launch_bounds__(256) void gather_bn(
    const unsigned short* __restrict__ xs, const int* __restrict__ rowptr,
    const int* __restrict__ col, const float* __restrict__ dinv,
    const float* __restrict__ b, unsigned short* __restrict__ t_out,
    float* __restrict__ stats, int N)
{
    __shared__ float lred[4][512];
    const int lane = threadIdx.x & 63;
    const int wid = threadIdx.x >> 6;
    const int c4 = lane * 4;
    const float4 bv = *(const float4*)(b + c4);

    float s0 = 0, s1 = 0, s2 = 0, s3 = 0;
    float q0 = 0, q1 = 0, q2 = 0, q3 = 0;

    const int w = (blockIdx.x * blockDim.x + threadIdx.x) >> 6;
    const int nw = (gridDim.x * blockDim.x) >> 6;

    for (int n0 = w; n0 < N; n0 += nw * 4) {
        const int nA = n0;
        const int nB = n0 + nw;
        const int nC = n0 + 2 * nw;
        const int nD = n0 + 3 * nw;
        const bool hB = nB < N, hC = nC < N, hD = nD < N;

        int eA = rowptr[nA], eA1 = rowptr[nA + 1];
        int eB = 0, eB1 = 0, eC = 0, eC1 = 0, eD = 0, eD1 = 0;
        if (hB) { eB = rowptr[nB]; eB1 = rowptr[nB + 1]; }
        if (hC) { eC = rowptr[nC]; eC1 = rowptr[nC + 1]; }
        if (hD) { eD = rowptr[nD]; eD1 = rowptr[nD + 1]; }

        float4 aA = ld4u(xs + (size_t)nA * 256 + c4);
        float4 aB = make_float4(0.f, 0.f, 0.f, 0.f), aC = aB, aD = aB;
        if (hB) aB = ld4u(xs + (size_t)nB * 256 + c4);
        if (hC) aC = ld4u(xs + (size_t)nC * 256 + c4);
        if (hD) aD = ld4u(xs + (size_t)nD * 256 + c4);

        while ((eA < eA1) | (eB < eB1) | (eC < eC1) | (eD < eD1)) {
            int sA = -1, sB = -1, sC = -1, sD = -1;
            if (eA < eA1) sA = col[eA++];
            if (eB < eB1) sB = col[eB++];
            if (eC < eC1) sC = col[eC++];
            if (eD < eD1) sD = col[eD++];
            float4 vA, vB, vC, vD;
            if (sA >= 0) vA = ld4u(xs + (size_t)sA * 256 + c4);
            if (sB >= 0) vB = ld4u(xs + (size_t)sB * 256 + c4);
            if (sC >= 0) vC = ld4u(xs + (size_t)sC * 256 + c4);
            if (sD >= 0) vD = ld4u(xs + (size_t)sD * 256 + c4);
            if (sA >= 0) { aA.x += vA.x; aA.y += vA.y; aA.z += vA.z; aA.w += vA.w; }
            if (sB >= 0) { aB.x += vB.x; aB.y += vB.y; aB.z += vB.z; aB.w += vB.w; }
            if (sC >= 0) { aC.x += vC.x; aC.y += vC.y; aC.z += vC.z; aC.w += vC.w; }
            if (sD >= 0) { aD.x += vD.x; aD.y += vD.y; aD.z += vD.z; aD.w += vD.w; }
        }

        {
            float di = dinv[nA];
            float4 t;
            t.x = fmaf(di, aA.x, bv.x); t.y = fmaf(di, aA.y, bv.y);
            t.z = fmaf(di, aA.z, bv.z); t.w = fmaf(di, aA.w, bv.w);
            st4u(t_out + (size_t)nA * 256 + c4, t);
            s0 += t.x; s1 += t.y; s2 += t.z; s3 += t.w;
            q0 += t.x * t.x; q1 += t.y * t.y; q2 += t.z * t.z; q3 += t.w * t.w;
        }
        if (hB) {
            float di = dinv[nB];
            float4 t;
            t.x = fmaf(di, aB.x, bv.x); t.y = fmaf(di, aB.y, bv.y);
            t.z = fmaf(di, aB.z, bv.z); t.w = fmaf(di, aB.w, bv.w);
            st4u(t_out + (size_t)nB * 256 + c4, t);
            s0 += t.x; s1 += t.y; s2 += t.z; s3 += t.w;
            q0 += t.x * t.x; q1 += t.y * t.y; q2 += t.z * t.z; q3 += t.w * t.w;
        }
        if (hC) {
            float di = dinv[nC];
            float4 t;
            t.x = fmaf(di, aC.x, bv.x); t.y = fmaf(di, aC.y, bv.y);
            t.z = fmaf(di, aC.z, bv.z); t.w = fmaf(di, aC.w, bv.w);
            st4u(t_out + (size_t)nC * 256 + c4, t);
            s0 += t.x; s1 += t.y; s2 += t.z; s3 += t.w;
            q0 += t.x * t.x; q1 += t.y * t.y; q2 += t.z * t.z; q3 += t.w * t.w;
        }
        if (hD) {
            float di = dinv[nD];
            float4 t;
            t.x = fmaf(di, aD.x, bv.x); t.y = fmaf(di, aD.y, bv.y);
            t.z = fmaf(di, aD.z, bv.z); t.w = fmaf(di, aD.w, bv.w);
            st4u(t_out + (size_t)nD * 256 + c4, t);
            s0 += t.x; s1 += t.y; s2 += t.z; s3 += t.w;
            q0 += t.x * t.x; q1 += t.y * t.y; q2 += t.z * t.z; q3 += t.w * t.w;
        }
    }

    lred[wid][c4 + 0] = s0; lred[wid][c4 + 1] = s1;
    lred[wid][c4 + 2] = s2; lred[wid][c4 + 3] = s3;
    lred[wid][256 + c4 + 0] = q0; lred[wid][256 + c4 + 1] = q1;
    lred[wid][256 + c4 + 2] = q2; lred[wid][256 + c4 + 3] = q3;
    __syncthreads();
    for (int i = threadIdx.x; i < 512; i += 256) {
        float v = lred[0][i] + lred[1][i] + lred[2][i] + lred[3][i];
        atomicAdd(&stats[i], v);
    }
}

__global__ void bn_finalize(const float* __restrict__ stats,
                            const float* __restrict__ g, const float* __restrict__ be,
                            float* __restrict__ ss, int N)
{
    int f = threadIdx.x;
    float m = stats[f] / (float)N;
    float v = stats[256 + f] / (float)N - m * m;
    float sc = g[f] * rsqrtf(v + 1e-5f);
    ss[f] = sc;
    ss[256 + f] = be[f] - m * sc;
}

// ---- segment pool (batch sorted): pooled[g] = sum relu(t*sc+sh) ------------
__global__ __launch_bounds__(256) void pool_seg(
    const unsigned short* __restrict__ t, const int* __restrict__ batch,
    const float* __restrict__ ss, float* __restrict__ pooled, int N)
{
    __shared__ float lred[4][256];
    const int g = blockIdx.x;
    const int lane = threadIdx.x & 63;
    const int wid = threadIdx.x >> 6;
    const int c4 = lane * 4;

    int lo = 0, hi = N;
    while (lo < hi) { int m = (lo + hi) >> 1; if (batch[m] < g) lo = m + 1; else hi = m; }
    const int start = lo;
    hi = N;
    while (lo < hi) { int m = (lo + hi) >> 1; if (batch[m] < g + 1) lo = m + 1; else hi = m; }
    const int end = lo;

    const float4 sc = *(const float4*)(ss + c4);
    const float4 sh = *(const float4*)(ss + 256 + c4);
    float4 acc = make_float4(0.f, 0.f, 0.f, 0.f);
    for (int r = start + wid; r < end; r += 4) {
        float4 a = ld4u(t + (size_t)r * 256 + c4);
        acc.x += fmaxf(fmaf(a.x, sc.x, sh.x), 0.f);
        acc.y += fmaxf(fmaf(a.y, sc.y, sh.y), 0.f);
        acc.z += fmaxf(fmaf(a.z, sc.z, sh.z), 0.f);
        acc.w += fmaxf(fmaf(a.w, sc.w, sh.w), 0.f);
    }
    lred[wid][c4 + 0] = acc.x; lred[wid][c4 + 1] = acc.y;
    lred[wid][c4 + 2] = acc.z; lred[wid][c4 + 3] = acc.w;
    __syncthreads();
    int i = threadIdx.x;
    pooled[(size_t)g * 256 + i] = lred[0][i] + lred[1][i] + lred[2][i] + lred[3][i];
}

// ---- fused MLP --------------------------------------------------------------
__global__ __launch_bounds__(256) void mlp_fused(
    const float* __restrict__ pooled,
    const float* __restrict__ LW1, const float* __restrict__ Lb1,
    const float* __restrict__ LW2, const float* __restrict__ Lb2,
    float* __restrict__ out)
{
    __shared__ float sp[256];
    __shared__ float red[256];
    const int g = blockIdx.x;
    const int t = threadIdx.x;
    sp[t] = pooled[(size_t)g * 256 + t];
    __syncthreads();
    float acc = Lb1[t];
    #pragma unroll 8
    for (int k = 0; k < 256; ++k) acc = fmaf(sp[k], LW1[k * 256 + t], acc);
    acc = fmaxf(acc, 0.f);
    red[t] = acc * LW2[t];
    __syncthreads();
    for (int s = 128; s > 0; s >>= 1) {
        if (t < s) red[t] += red[t + s];
        __syncthreads();
    }
    if (t == 0) out[g] = red[0] + Lb2[0];
}

// ---------------------------------------------------------------------------
extern "C" void kernel_launch(void* const* d_in, const int* in_sizes, int n_in,
                              void* d_out, int out_size, void* d_ws, size_t ws_size,
                              hipStream_t stream)
{
    const float* x    = (const float*)d_in[0];
    const int*   ei   = (const int*)d_in[1];
    const int*   batch= (const int*)d_in[2];
    const float* W1 = (const float*)d_in[3];  const float* b1 = (const float*)d_in[4];
    const float* W2 = (const float*)d_in[5];  const float* b2 = (const float*)d_in[6];
    const float* W3 = (const float*)d_in[7];  const float* b3 = (const float*)d_in[8];
    const float* g1 = (const float*)d_in[9];  const float* be1= (const float*)d_in[10];
    const float* g2 = (const float*)d_in[11]; const float* be2= (const float*)d_in[12];
    const float* g3 = (const float*)d_in[13]; const float* be3= (const float*)d_in[14];
    const float* LW1= (const float*)d_in[15]; const float* Lb1= (const float*)d_in[16];
    const float* LW2= (const float*)d_in[17]; const float* Lb2= (const float*)d_in[18];

    const int N = in_sizes[2];            // 100000
    const int E = in_sizes[1] / 2;        // 300000
    const int F = in_sizes[0] / N;        // 128
    const int H = in_sizes[4];            // 256
    const int G = out_size;               // 2048
    const int Mp = (N + 127) & ~127;
    const int NB = (N + 511) / 512;
    const int* src = ei;
    const int* dst = ei + E;
    const size_t NHp = (size_t)Mp * H;

    const float* Wl[3] = {W1, W2, W3};
    const float* bl[3] = {b1, b2, b3};
    const float* gl[3] = {g1, g2, g3};
    const float* bel[3]= {be1, be2, be3};

    // ---- workspace layout ----
    char* p = (char*)d_ws;
    unsigned short* TB = (unsigned short*)p;  p += NHp * 2;       // t  [Mp,256] bf16
    unsigned short* XS = (unsigned short*)p;  p += NHp * 2;       // xs [Mp,256] bf16
    unsigned short* XB = (unsigned short*)p;  p += (size_t)Mp * 128 * 2;  // x bf16
    float* dinv = (float*)p;           p += (((size_t)Mp * 4) + 255) & ~(size_t)255;
    int* degi  = (int*)p;              p += (((size_t)N * 4) + 255) & ~(size_t)255;
    float* stats = (float*)p;          p += 2048;
    float* ss    = (float*)p;          p += 2048;
    int* psum   = (int*)p;             p += 4096;
    int* poff   = (int*)p;             p += 4096;
    float* pooled= (float*)p;          p += (size_t)G * H * 4;
    int* rowptr = (int*)p;             p += (((size_t)(N + 1) * 4) + 255) & ~(size_t)255;
    int* col    = (int*)p;             p += (((size_t)E * 4) + 255) & ~(size_t)255;
    unsigned short* WTb = (unsigned short*)p;  p += (size_t)H * H * 2;

    // CSR build + dinv
    hipMemsetAsync(degi, 0, (size_t)N * sizeof(int), stream);
    count_deg_i<<<1024, 256, 0, stream>>>(dst, degi, E);
    scan_partial<<<NB, 256, 0, stream>>>(degi, psum, N);
    scan_offsets<<<1, 1024, 0, stream>>>(psum, poff, NB, rowptr, N);
    write_rowptr<<<NB, 256, 0, stream>>>(degi, poff, rowptr, N);
    dinv_from_rowptr<<<(N + 255) / 256, 256, 0, stream>>>(rowptr, dinv, N);
    hipMemsetAsync(degi, 0, (size_t)N * sizeof(int), stream);
    fill_csr<<<1024, 256, 0, stream>>>(src, dst, rowptr, degi, col, E);

    // x -> bf16
    conv_bf16<<<2048, 256, 0, stream>>>(x, XB, (size_t)N * F / 4);

    for (int L = 0; L < 3; ++L) {
        const int K = (L == 0) ? F : H;
        make_wt<<<(K * 256 + 255) / 256, 256, 0, stream>>>(Wl[L], WTb, K);
        dim3 grid(Mp / 128, H / 128);
        if (L == 0)
            gemm_mfma<0><<<grid, 256, 0, stream>>>(XB, WTb, dinv, nullptr, XS, K);
        else
            gemm_mfma<1><<<grid, 256, 0, stream>>>(TB, WTb, dinv, ss, XS, K);
        hipMemsetAsync(stats, 0, 512 * sizeof(float), stream);
        gather_bn<<<1024, 256, 0, stream>>>(XS, rowptr, col, dinv, bl[L], TB, stats, N);
        bn_finalize<<<1, 256, 0, stream>>>(stats, gl[L], bel[L], ss, N);
    }

    pool_seg<<<G, 256, 0, stream>>>(TB, batch, ss, pooled, N);
    mlp_fused<<<G, 256, 0, stream>>>(pooled, LW1, Lb1, LW2, Lb2, (float*)d_out);
}